// Round 9
// baseline (646.644 us; speedup 1.0000x reference)
//
#include <hip/hip_runtime.h>

#define D    300
#define D4   75    // D / 4 float4 chunks
#define KPAD 320   // K padded to 10 MFMA k-steps of 32
#define BM   256
#define BN   64
#define BK   32
#define LDT  40    // LDS row stride in bf16 (80 B: 16B-aligned, 8-residue bank spread)
#define NNB  5     // n-blocks per m-panel (ceil(300/64))

typedef short bf16x8 __attribute__((ext_vector_type(8)));
typedef float f32x4  __attribute__((ext_vector_type(4)));

__device__ inline short f2bh(float f) {           // fp32 -> bf16 RNE (bit trick)
    unsigned u = __float_as_uint(f);
    unsigned r = (u + 0x7FFFu + ((u >> 16) & 1u)) >> 16;
    return (short)r;
}
__device__ inline float bh2f(short s) {
    return __uint_as_float(((unsigned)(unsigned short)s) << 16);
}

// ---------------- embedding -> split bf16 pair (k-padded layout) ----------------
__global__ __launch_bounds__(256) void embed_kernel(const int* __restrict__ x,
                                                    const float4* __restrict__ atomT,
                                                    const float4* __restrict__ wordT,
                                                    short* __restrict__ hH, short* __restrict__ hL, int N) {
    int idx = blockIdx.x * blockDim.x + threadIdx.x;
    if (idx >= N * D4) return;
    int n = idx / D4, c = idx % D4;
    int a = x[n * 2 + 0];
    int w = x[n * 2 + 1];
    float4 va = atomT[(size_t)a * D4 + c];
    float4 vw = wordT[(size_t)w * D4 + c];
    float4 v = make_float4(va.x + vw.x, va.y + vw.y, va.z + vw.z, va.w + vw.w);
    short4 hh, ll;
    hh.x = f2bh(v.x); ll.x = f2bh(v.x - bh2f(hh.x));
    hh.y = f2bh(v.y); ll.y = f2bh(v.y - bh2f(hh.y));
    hh.z = f2bh(v.z); ll.z = f2bh(v.z - bh2f(hh.z));
    hh.w = f2bh(v.w); ll.w = f2bh(v.w - bh2f(hh.w));
    *(short4*)&hH[(size_t)n * KPAD + c * 4] = hh;
    *(short4*)&hL[(size_t)n * KPAD + c * 4] = ll;
}

// ---------------- W -> transposed, k-padded, split-bf16 pair ----------------
__global__ __launch_bounds__(256) void wprep_kernel(const float* __restrict__ W,
                                                    short* __restrict__ wh, short* __restrict__ wl) {
    int id = blockIdx.x * blockDim.x + threadIdx.x;
    if (id >= D * KPAD) return;
    int n = id / KPAD, k = id % KPAD;
    float v = (k < D) ? W[(size_t)k * D + n] : 0.f;
    short hh = f2bh(v);
    short ll = f2bh(v - bh2f(hh));
    wh[id] = hh; wl[id] = ll;
}

// ---------------- CSR build ----------------
__global__ __launch_bounds__(256) void cnt_kernel(const int* __restrict__ dst, int* __restrict__ cnt, int E) {
    int i = blockIdx.x * blockDim.x + threadIdx.x;
    if (i < E) atomicAdd(&cnt[dst[i]], 1);
}
__global__ __launch_bounds__(256) void dinv_kernel(const int* __restrict__ cnt, float* __restrict__ dinv, int N) {
    int i = blockIdx.x * blockDim.x + threadIdx.x;
    if (i < N) dinv[i] = rsqrtf((float)(cnt[i] + 1));   // +1 self-loop
}
__global__ __launch_bounds__(1024) void scan_kernel(const int* __restrict__ cnt,
                                                    int* __restrict__ off, int* __restrict__ cursor, int N) {
    __shared__ int warp_sums[16];
    __shared__ int chunk_base;
    const int tid = threadIdx.x;
    const int lane = tid & 63;
    const int wid = tid >> 6;
    if (tid == 0) chunk_base = 0;
    __syncthreads();
    for (int base = 0; base < N; base += 1024) {
        int i = base + tid;
        int v = (i < N) ? cnt[i] : 0;
        int s = v;
        #pragma unroll
        for (int d = 1; d < 64; d <<= 1) {
            int t = __shfl_up(s, d, 64);
            if (lane >= d) s += t;
        }
        if (lane == 63) warp_sums[wid] = s;
        __syncthreads();
        if (wid == 0) {
            int ws = (lane < 16) ? warp_sums[lane] : 0;
            #pragma unroll
            for (int d = 1; d < 16; d <<= 1) {
                int t = __shfl_up(ws, d, 64);
                if (lane >= d) ws += t;
            }
            if (lane < 16) warp_sums[lane] = ws;
        }
        __syncthreads();
        int excl = chunk_base + (wid ? warp_sums[wid - 1] : 0) + s - v;
        if (i < N) { off[i] = excl; cursor[i] = excl; }
        int total = warp_sums[15];
        __syncthreads();
        if (tid == 0) chunk_base += total;
        __syncthreads();
    }
    if (tid == 0) off[N] = chunk_base;
}
__global__ __launch_bounds__(256) void fill_kernel(const int* __restrict__ src, const int* __restrict__ dst,
                                                   const float* __restrict__ dinv, int* __restrict__ cursor,
                                                   int* __restrict__ csr_src, float* __restrict__ csr_w, int E) {
    int e = blockIdx.x * blockDim.x + threadIdx.x;
    if (e >= E) return;
    int s = src[e], d = dst[e];
    int slot = atomicAdd(&cursor[d], 1);
    csr_src[slot] = s;
    csr_w[slot] = dinv[s] * dinv[d];
}

// ---------------- GEMM via MFMA, split-bf16 (pre-split A): C = A @ W ----------------
// 1D grid, XCD-swizzled: d = q*(8*NNB) + nb*8 + r, mb = q*8 + r.
// BM=256: 4 waves x 4 m-frags each -> 48 MFMAs per 16 ds_read_b128.
__global__ __launch_bounds__(256) void gemm_mfma(const short* __restrict__ AH,
                                                 const short* __restrict__ AL,
                                                 const short* __restrict__ WtH,
                                                 const short* __restrict__ WtL,
                                                 float* __restrict__ C, int M) {
    const int d_lin = blockIdx.x;
    const int q   = d_lin / (8 * NNB);
    const int rem = d_lin % (8 * NNB);
    const int nb  = rem >> 3;
    const int r   = rem & 7;
    const int mb  = q * 8 + r;
    if (mb * BM >= M) return;
    const int bm = mb * BM;
    const int n0 = nb * BN;

    __shared__ short AsH[BM][LDT], AsL[BM][LDT];   // 2 x 20 KB
    __shared__ short BsH[BN][LDT], BsL[BN][LDT];   // 2 x 5 KB

    const int tid = threadIdx.x;
    const int lane = tid & 63, wid = tid >> 6;
    const int g4 = lane >> 4, l16 = lane & 15;
    const int wr0 = wid * 64;

    f32x4 acc[4][4];
    #pragma unroll
    for (int i = 0; i < 4; ++i)
        #pragma unroll
        for (int j = 0; j < 4; ++j) acc[i][j] = (f32x4)0.0f;

    for (int k0 = 0; k0 < KPAD; k0 += BK) {
        // ---- stage A: 256x32 bf16 pair (1024 16B chunks per array) ----
        #pragma unroll
        for (int i = 0; i < 4; ++i) {
            int g = tid + i * 256;
            int rr = g >> 2, kc = (g & 3) * 8;
            int gr = bm + rr;
            bf16x8 vh = (bf16x8)(short)0, vl = (bf16x8)(short)0;
            if (gr < M) {
                vh = *(const bf16x8*)&AH[(size_t)gr * KPAD + k0 + kc];
                vl = *(const bf16x8*)&AL[(size_t)gr * KPAD + k0 + kc];
            }
            *(bf16x8*)&AsH[rr][kc] = vh;
            *(bf16x8*)&AsL[rr][kc] = vl;
        }
        // ---- stage B: 64x32 bf16 pair ----
        {
            int g = tid;
            int rr = g >> 2, kc = (g & 3) * 8;
            int gn = n0 + rr;
            bf16x8 vh = (bf16x8)(short)0, vl = (bf16x8)(short)0;
            if (gn < D) {
                vh = *(const bf16x8*)&WtH[(size_t)gn * KPAD + k0 + kc];
                vl = *(const bf16x8*)&WtL[(size_t)gn * KPAD + k0 + kc];
            }
            *(bf16x8*)&BsH[rr][kc] = vh;
            *(bf16x8*)&BsL[rr][kc] = vl;
        }
        __syncthreads();

        bf16x8 ah[4], al[4], bh[4], bl[4];
        #pragma unroll
        for (int mf = 0; mf < 4; ++mf) {
            int row = wr0 + mf * 16 + l16;
            ah[mf] = *(const bf16x8*)&AsH[row][g4 * 8];
            al[mf] = *(const bf16x8*)&AsL[row][g4 * 8];
        }
        #pragma unroll
        for (int nf = 0; nf < 4; ++nf) {
            int col = nf * 16 + l16;
            bh[nf] = *(const bf16x8*)&BsH[col][g4 * 8];
            bl[nf] = *(const bf16x8*)&BsL[col][g4 * 8];
        }
        #pragma unroll
        for (int mf = 0; mf < 4; ++mf)
            #pragma unroll
            for (int nf = 0; nf < 4; ++nf) {
                acc[mf][nf] = __builtin_amdgcn_mfma_f32_16x16x32_bf16(ah[mf], bh[nf], acc[mf][nf], 0, 0, 0);
                acc[mf][nf] = __builtin_amdgcn_mfma_f32_16x16x32_bf16(ah[mf], bl[nf], acc[mf][nf], 0, 0, 0);
                acc[mf][nf] = __builtin_amdgcn_mfma_f32_16x16x32_bf16(al[mf], bh[nf], acc[mf][nf], 0, 0, 0);
            }
        __syncthreads();
    }

    // ---- C write: row=(lane>>4)*4+reg, col=lane&15 per 16x16 frag ----
    #pragma unroll
    for (int mf = 0; mf < 4; ++mf)
        #pragma unroll
        for (int nf = 0; nf < 4; ++nf)
            #pragma unroll
            for (int reg = 0; reg < 4; ++reg) {
                int grow = bm + wr0 + mf * 16 + g4 * 4 + reg;
                int gcol = n0 + nf * 16 + l16;
                if (grow < M && gcol < D)
                    C[(size_t)grow * D + gcol] = acc[mf][nf][reg];
            }
}

// ---------------- hop aggregate (gather, software-pipelined) ----------------
__global__ __launch_bounds__(256) void gather_kernel(const float4* __restrict__ hl,
                                                     const int* __restrict__ off,
                                                     const int* __restrict__ csr_src,
                                                     const float* __restrict__ csr_w,
                                                     const float* __restrict__ dinv,
                                                     const float4* __restrict__ bias4,
                                                     short* __restrict__ hH, short* __restrict__ hL, int N) {
    int idx = blockIdx.x * blockDim.x + threadIdx.x;
    if (idx >= N * D4) return;
    int n = idx / D4, c = idx - n * D4;
    float s = dinv[n]; s = s * s;
    float4 v = hl[idx];
    float4 bb = bias4[c];
    float4 acc = make_float4(bb.x + v.x * s, bb.y + v.y * s, bb.z + v.z * s, bb.w + v.w * s);

    const int j0 = off[n], j1 = off[n + 1];
    // 1-ahead index prefetch + double-buffered row load: 2 row-loads in flight.
    int   snN = 0;  float wN = 0.f;
    if (j0 < j1) { snN = csr_src[j0]; wN = csr_w[j0]; }
    float4 uA = make_float4(0.f, 0.f, 0.f, 0.f);
    float  wA = wN;
    if (j0 < j1) uA = hl[(size_t)snN * D4 + c];
    for (int j = j0; j < j1; ++j) {
        int jn = j + 1;
        float4 uB = make_float4(0.f, 0.f, 0.f, 0.f);
        float  wB = 0.f;
        if (jn < j1) {
            int snB = csr_src[jn]; wB = csr_w[jn];
            uB = hl[(size_t)snB * D4 + c];      // issues before the FMAs wait on uA
        }
        acc.x += uA.x * wA; acc.y += uA.y * wA;
        acc.z += uA.z * wA; acc.w += uA.w * wA;
        uA = uB; wA = wB;
    }

    short4 hh, ll;
    hh.x = f2bh(acc.x); ll.x = f2bh(acc.x - bh2f(hh.x));
    hh.y = f2bh(acc.y); ll.y = f2bh(acc.y - bh2f(hh.y));
    hh.z = f2bh(acc.z); ll.z = f2bh(acc.z - bh2f(hh.z));
    hh.w = f2bh(acc.w); ll.w = f2bh(acc.w - bh2f(hh.w));
    *(short4*)&hH[(size_t)n * KPAD + c * 4] = hh;
    *(short4*)&hL[(size_t)n * KPAD + c * 4] = ll;
}

// ---------------- pooling via sorted-batch segments ----------------
__global__ __launch_bounds__(256) void seg_start_kernel(const int* __restrict__ batch,
                                                        int* __restrict__ start, int N, int G) {
    int i = blockIdx.x * blockDim.x + threadIdx.x;
    if (i >= N) return;
    int b = batch[i];
    int prev = (i == 0) ? -1 : batch[i - 1];
    for (int g = prev + 1; g <= b; ++g) start[g] = i;
    if (i == N - 1)
        for (int g = b + 1; g <= G; ++g) start[g] = N;
}
__global__ __launch_bounds__(256) void pool_seg(const short* __restrict__ hH,
                                                const short* __restrict__ hL,
                                                const int* __restrict__ start,
                                                float* __restrict__ out, int G) {
    int g = blockIdx.x;
    if (g >= G) return;
    int j0 = start[g], j1 = start[g + 1];
    float inv = (j1 > j0) ? 1.0f / (float)(j1 - j0) : 0.0f;
    for (int c = threadIdx.x; c < D; c += 256) {
        float acc = 0.f;
        for (int n = j0; n < j1; ++n)
            acc += bh2f(hH[(size_t)n * KPAD + c]) + bh2f(hL[(size_t)n * KPAD + c]);
        out[(size_t)g * D + c] = acc * inv;
    }
}

extern "C" void kernel_launch(void* const* d_in, const int* in_sizes, int n_in,
                              void* d_out, int out_size, void* d_ws, size_t ws_size,
                              hipStream_t stream) {
    (void)n_in; (void)ws_size;
    const int*   x     = (const int*)d_in[0];
    const int*   ei    = (const int*)d_in[1];
    const int*   batch = (const int*)d_in[2];
    // d_in[3] = num_hops (fixed 4)
    const float* atomT = (const float*)d_in[4];
    const float* wordT = (const float*)d_in[5];
    const float* W     = (const float*)d_in[6];
    const float* bias  = (const float*)d_in[7];

    const int N = in_sizes[0] / 2;
    const int E = in_sizes[1] / 2;
    const int G = out_size / D;
    const int NUM_HOPS = 4;

    const int* src = ei;
    const int* dst = ei + E;

    // workspace layout (all segment starts 16B-aligned)
    float* hl      = (float*)d_ws;                    // N*D f32
    float* dinv    = hl + (size_t)N * D;              // N
    float* csr_w   = dinv + N;                        // E
    short* wtH     = (short*)(csr_w + E);             // D*KPAD bf16
    short* wtL     = wtH + (size_t)D * KPAD;          // D*KPAD bf16
    short* hH      = wtL + (size_t)D * KPAD;          // N*KPAD bf16
    short* hLo     = hH + (size_t)N * KPAD;           // N*KPAD bf16
    int*   cnt     = (int*)(hLo + (size_t)N * KPAD);  // N
    int*   off     = cnt + N;                         // N+1
    int*   cursor  = off + N + 1;                     // N
    int*   csr_src = cursor + N;                      // E
    int*   start   = csr_src + E;                     // G+1

    const int B = 256;
    int ndBlocks = (N * D4 + B - 1) / B;

    // zero the k-pad columns (embed/gather only write c<300)
    hipMemsetAsync(hH, 0, (size_t)N * KPAD * sizeof(short), stream);
    hipMemsetAsync(hLo, 0, (size_t)N * KPAD * sizeof(short), stream);

    embed_kernel<<<ndBlocks, B, 0, stream>>>(x, (const float4*)atomT, (const float4*)wordT, hH, hLo, N);
    wprep_kernel<<<(D * KPAD + B - 1) / B, B, 0, stream>>>(W, wtH, wtL);

    hipMemsetAsync(cnt, 0, (size_t)N * sizeof(int), stream);
    cnt_kernel <<<(E + B - 1) / B, B, 0, stream>>>(dst, cnt, E);
    dinv_kernel<<<(N + B - 1) / B, B, 0, stream>>>(cnt, dinv, N);
    scan_kernel<<<1, 1024, 0, stream>>>(cnt, off, cursor, N);
    fill_kernel<<<(E + B - 1) / B, B, 0, stream>>>(src, dst, dinv, cursor, csr_src, csr_w, E);
    seg_start_kernel<<<(N + B - 1) / B, B, 0, stream>>>(batch, start, N, G);

    // XCD-swizzled 1D grid: ceil(nm/8) groups x 8 m-slots x NNB n-blocks
    const int nmB = (N + BM - 1) / BM;
    const int gemmBlocks = ((nmB + 7) / 8) * 8 * NNB;
    for (int hop = 0; hop < NUM_HOPS; ++hop) {
        gemm_mfma    <<<gemmBlocks, 256, 0, stream>>>(hH, hLo, wtH, wtL, hl, N);
        gather_kernel<<<ndBlocks, B, 0, stream>>>((const float4*)hl, off, csr_src, csr_w, dinv,
                                                  (const float4*)bias, hH, hLo, N);
    }

    pool_seg<<<G, B, 0, stream>>>(hH, hLo, start, (float*)d_out, G);
}

// Round 10
// 591.655 us; speedup vs baseline: 1.0929x; 1.0929x over previous
//
#include <hip/hip_runtime.h>

#define D    300
#define D4   75    // D/4 float4 chunks
#define KPAD 320   // GEMM K padded to 10 k-steps of 32
#define BM   128
#define BN   64
#define LDT  40    // LDS row stride in bf16 (80 B: 16B-aligned, bank-spread)
#define NNB  5     // n-blocks per m-panel

typedef short bf16x8 __attribute__((ext_vector_type(8)));
typedef float f32x4  __attribute__((ext_vector_type(4)));

__device__ inline short f2bh(float f) {           // fp32 -> bf16 RNE
    unsigned u = __float_as_uint(f);
    unsigned r = (u + 0x7FFFu + ((u >> 16) & 1u)) >> 16;
    return (short)r;
}
__device__ inline float bh2f(short s) {
    return __uint_as_float(((unsigned)(unsigned short)s) << 16);
}

// ---------------- embedding -> fp32 h0 ----------------
__global__ __launch_bounds__(256) void embed_f32(const int* __restrict__ x,
                                                 const float4* __restrict__ atomT,
                                                 const float4* __restrict__ wordT,
                                                 float4* __restrict__ h, int N) {
    int idx = blockIdx.x * blockDim.x + threadIdx.x;
    if (idx >= N * D4) return;
    int n = idx / D4, c = idx % D4;
    int a = x[n * 2 + 0];
    int w = x[n * 2 + 1];
    float4 va = atomT[(size_t)a * D4 + c];
    float4 vw = wordT[(size_t)w * D4 + c];
    h[idx] = make_float4(va.x + vw.x, va.y + vw.y, va.z + vw.z, va.w + vw.w);
}

// ---------------- CSR build ----------------
__global__ __launch_bounds__(256) void cnt_kernel(const int* __restrict__ dst, int* __restrict__ cnt, int E) {
    int i = blockIdx.x * blockDim.x + threadIdx.x;
    if (i < E) atomicAdd(&cnt[dst[i]], 1);
}
__global__ __launch_bounds__(256) void dinv_kernel(const int* __restrict__ cnt, float* __restrict__ dinv, int N) {
    int i = blockIdx.x * blockDim.x + threadIdx.x;
    if (i < N) dinv[i] = rsqrtf((float)(cnt[i] + 1));   // +1 self-loop
}
__global__ __launch_bounds__(1024) void scan_kernel(const int* __restrict__ cnt,
                                                    int* __restrict__ off, int* __restrict__ cursor, int N) {
    __shared__ int warp_sums[16];
    __shared__ int chunk_base;
    const int tid = threadIdx.x;
    const int lane = tid & 63;
    const int wid = tid >> 6;
    if (tid == 0) chunk_base = 0;
    __syncthreads();
    for (int base = 0; base < N; base += 1024) {
        int i = base + tid;
        int v = (i < N) ? cnt[i] : 0;
        int s = v;
        #pragma unroll
        for (int d = 1; d < 64; d <<= 1) {
            int t = __shfl_up(s, d, 64);
            if (lane >= d) s += t;
        }
        if (lane == 63) warp_sums[wid] = s;
        __syncthreads();
        if (wid == 0) {
            int ws = (lane < 16) ? warp_sums[lane] : 0;
            #pragma unroll
            for (int d = 1; d < 16; d <<= 1) {
                int t = __shfl_up(ws, d, 64);
                if (lane >= d) ws += t;
            }
            if (lane < 16) warp_sums[lane] = ws;
        }
        __syncthreads();
        int excl = chunk_base + (wid ? warp_sums[wid - 1] : 0) + s - v;
        if (i < N) { off[i] = excl; cursor[i] = excl; }
        int total = warp_sums[15];
        __syncthreads();
        if (tid == 0) chunk_base += total;
        __syncthreads();
    }
    if (tid == 0) off[N] = chunk_base;
}
__global__ __launch_bounds__(256) void fill_kernel(const int* __restrict__ src, const int* __restrict__ dst,
                                                   const float* __restrict__ dinv, int* __restrict__ cursor,
                                                   int* __restrict__ csr_src, float* __restrict__ csr_w, int E) {
    int e = blockIdx.x * blockDim.x + threadIdx.x;
    if (e >= E) return;
    int s = src[e], d = dst[e];
    int slot = atomicAdd(&cursor[d], 1);
    csr_src[slot] = s;
    csr_w[slot] = dinv[s] * dinv[d];
}

// ---------------- ones + vector gather (u_k = A^k 1) ----------------
__global__ __launch_bounds__(256) void ones_kernel(float* __restrict__ v, int N) {
    int i = blockIdx.x * blockDim.x + threadIdx.x;
    if (i < N) v[i] = 1.0f;
}
__global__ __launch_bounds__(256) void gather_vec(const float* __restrict__ in,
                                                  const int* __restrict__ off,
                                                  const int* __restrict__ csr_src,
                                                  const float* __restrict__ csr_w,
                                                  const float* __restrict__ dinv,
                                                  float* __restrict__ out, int N) {
    int n = blockIdx.x * blockDim.x + threadIdx.x;
    if (n >= N) return;
    float s = dinv[n];
    float acc = in[n] * s * s;
    int j1 = off[n + 1];
    for (int j = off[n]; j < j1; ++j) acc += csr_w[j] * in[csr_src[j]];
    out[n] = acc;
}

// ---------------- small fp32 GEMM 300x300 (L2-resident): C = A@B ----------------
__global__ __launch_bounds__(256) void sgemm300(const float* __restrict__ A,
                                                const float* __restrict__ B,
                                                float* __restrict__ C) {
    int id = blockIdx.x * blockDim.x + threadIdx.x;
    if (id >= D * D) return;
    int i = id / D, j = id % D;
    float acc = 0.f;
    #pragma unroll 4
    for (int k = 0; k < D; ++k) acc = fmaf(A[i * D + k], B[k * D + j], acc);
    C[id] = acc;
}
// ---------------- GEMV: out[j] = sum_k in[k] * W[k][j] ----------------
__global__ __launch_bounds__(256) void gemv300(const float* __restrict__ in,
                                               const float* __restrict__ W,
                                               float* __restrict__ out) {
    int j = blockIdx.x * blockDim.x + threadIdx.x;
    if (j >= D) return;
    float acc = 0.f;
    #pragma unroll 4
    for (int k = 0; k < D; ++k) acc = fmaf(in[k], W[k * D + j], acc);
    out[j] = acc;
}

// ---------------- W4 -> transposed, k-padded, split-bf16 pair ----------------
__global__ __launch_bounds__(256) void wprep_kernel(const float* __restrict__ W,
                                                    short* __restrict__ wh, short* __restrict__ wl) {
    int id = blockIdx.x * blockDim.x + threadIdx.x;
    if (id >= D * KPAD) return;
    int n = id / KPAD, k = id % KPAD;
    float v = (k < D) ? W[(size_t)k * D + n] : 0.f;
    short hh = f2bh(v);
    short ll = f2bh(v - bh2f(hh));
    wh[id] = hh; wl[id] = ll;
}

// ---------------- sparse hop: out = A_hat * in  (fp32, no bias) ----------------
__global__ __launch_bounds__(256) void gather_f32(const float4* __restrict__ in,
                                                  const int* __restrict__ off,
                                                  const int* __restrict__ csr_src,
                                                  const float* __restrict__ csr_w,
                                                  const float* __restrict__ dinv,
                                                  float4* __restrict__ out, int N) {
    int idx = blockIdx.x * blockDim.x + threadIdx.x;
    if (idx >= N * D4) return;
    int n = idx / D4, c = idx - n * D4;
    float s = dinv[n]; s = s * s;
    float4 v = in[idx];
    float4 acc = make_float4(v.x * s, v.y * s, v.z * s, v.w * s);
    int j0 = off[n], j1 = off[n + 1];
    for (int j = j0; j < j1; ++j) {
        int sn = csr_src[j];
        float w = csr_w[j];
        float4 u = in[(size_t)sn * D4 + c];
        acc.x += u.x * w; acc.y += u.y * w; acc.z += u.z * w; acc.w += u.w * w;
    }
    out[idx] = acc;
}

// ---------------- single GEMM: h4 = g4 @ W4 + u3*w3b + u2*w2b + u1*w1b + b ----------------
// A fp32 [M][300] split on the fly; W4t pre-split bf16 [300][KPAD].
// XCD-swizzled 1D grid: d = q*(8*NNB) + nb*8 + r, mb = q*8 + r.
__global__ __launch_bounds__(256) void gemm_mfma(const float* __restrict__ A,
                                                 const short* __restrict__ WtH,
                                                 const short* __restrict__ WtL,
                                                 const float* __restrict__ u1,
                                                 const float* __restrict__ u2,
                                                 const float* __restrict__ u3,
                                                 const float* __restrict__ w1b,
                                                 const float* __restrict__ w2b,
                                                 const float* __restrict__ w3b,
                                                 const float* __restrict__ bias,
                                                 float* __restrict__ C, int M) {
    const int d_lin = blockIdx.x;
    const int q   = d_lin / (8 * NNB);
    const int rem = d_lin % (8 * NNB);
    const int nb  = rem >> 3;
    const int r   = rem & 7;
    const int mb  = q * 8 + r;
    if (mb * BM >= M) return;
    const int bm = mb * BM;
    const int n0 = nb * BN;

    __shared__ short AsH[BM][LDT], AsL[BM][LDT];
    __shared__ short BsH[BN][LDT], BsL[BN][LDT];

    const int tid = threadIdx.x;
    const int lane = tid & 63, wid = tid >> 6;
    const int g4 = lane >> 4, l16 = lane & 15;
    const int wr0 = wid * 32;

    f32x4 acc[2][4];
    #pragma unroll
    for (int i = 0; i < 2; ++i)
        #pragma unroll
        for (int j = 0; j < 4; ++j) acc[i][j] = (f32x4)0.0f;

    for (int k0 = 0; k0 < KPAD; k0 += 32) {
        // ---- stage A: 128x32 fp32 -> split bf16 (1024 float4 chunks, 4/thread) ----
        #pragma unroll
        for (int i = 0; i < 4; ++i) {
            int g = tid + i * 256;
            int rr = g >> 3, ck = (g & 7) * 4;
            int gr = bm + rr, gk = k0 + ck;
            float4 v = make_float4(0.f, 0.f, 0.f, 0.f);
            if (gr < M && gk < D) v = *(const float4*)&A[(size_t)gr * D + gk];
            short4 hh, ll;
            hh.x = f2bh(v.x); ll.x = f2bh(v.x - bh2f(hh.x));
            hh.y = f2bh(v.y); ll.y = f2bh(v.y - bh2f(hh.y));
            hh.z = f2bh(v.z); ll.z = f2bh(v.z - bh2f(hh.z));
            hh.w = f2bh(v.w); ll.w = f2bh(v.w - bh2f(hh.w));
            *(short4*)&AsH[rr][ck] = hh;
            *(short4*)&AsL[rr][ck] = ll;
        }
        // ---- stage B: 64x32 bf16 pair (16B chunks) ----
        {
            int g = tid;
            int rr = g >> 2, kc = (g & 3) * 8;
            int gn = n0 + rr;
            bf16x8 vh = (bf16x8)(short)0, vl = (bf16x8)(short)0;
            if (gn < D) {
                vh = *(const bf16x8*)&WtH[(size_t)gn * KPAD + k0 + kc];
                vl = *(const bf16x8*)&WtL[(size_t)gn * KPAD + k0 + kc];
            }
            *(bf16x8*)&BsH[rr][kc] = vh;
            *(bf16x8*)&BsL[rr][kc] = vl;
        }
        __syncthreads();

        bf16x8 ah[2], al[2], bh[4], bl[4];
        #pragma unroll
        for (int mf = 0; mf < 2; ++mf) {
            int row = wr0 + mf * 16 + l16;
            ah[mf] = *(const bf16x8*)&AsH[row][g4 * 8];
            al[mf] = *(const bf16x8*)&AsL[row][g4 * 8];
        }
        #pragma unroll
        for (int nf = 0; nf < 4; ++nf) {
            int col = nf * 16 + l16;
            bh[nf] = *(const bf16x8*)&BsH[col][g4 * 8];
            bl[nf] = *(const bf16x8*)&BsL[col][g4 * 8];
        }
        #pragma unroll
        for (int mf = 0; mf < 2; ++mf)
            #pragma unroll
            for (int nf = 0; nf < 4; ++nf) {
                acc[mf][nf] = __builtin_amdgcn_mfma_f32_16x16x32_bf16(ah[mf], bh[nf], acc[mf][nf], 0, 0, 0);
                acc[mf][nf] = __builtin_amdgcn_mfma_f32_16x16x32_bf16(ah[mf], bl[nf], acc[mf][nf], 0, 0, 0);
                acc[mf][nf] = __builtin_amdgcn_mfma_f32_16x16x32_bf16(al[mf], bh[nf], acc[mf][nf], 0, 0, 0);
            }
        __syncthreads();
    }

    // ---- epilogue: rank-1 bias terms + C write (row=(lane>>4)*4+reg, col=lane&15) ----
    #pragma unroll
    for (int mf = 0; mf < 2; ++mf)
        #pragma unroll
        for (int nf = 0; nf < 4; ++nf)
            #pragma unroll
            for (int reg = 0; reg < 4; ++reg) {
                int grow = bm + wr0 + mf * 16 + g4 * 4 + reg;
                int gcol = n0 + nf * 16 + l16;
                if (grow < M && gcol < D) {
                    float v = acc[mf][nf][reg]
                            + u1[grow] * w1b[gcol]
                            + u2[grow] * w2b[gcol]
                            + u3[grow] * w3b[gcol]
                            + bias[gcol];
                    C[(size_t)grow * D + gcol] = v;
                }
            }
}

// ---------------- pooling via sorted-batch segments (fp32 h4) ----------------
__global__ __launch_bounds__(256) void seg_start_kernel(const int* __restrict__ batch,
                                                        int* __restrict__ start, int N, int G) {
    int i = blockIdx.x * blockDim.x + threadIdx.x;
    if (i >= N) return;
    int b = batch[i];
    int prev = (i == 0) ? -1 : batch[i - 1];
    for (int g = prev + 1; g <= b; ++g) start[g] = i;
    if (i == N - 1)
        for (int g = b + 1; g <= G; ++g) start[g] = N;
}
__global__ __launch_bounds__(256) void pool_seg(const float* __restrict__ h,
                                                const int* __restrict__ start,
                                                float* __restrict__ out, int G) {
    int g = blockIdx.x;
    if (g >= G) return;
    int j0 = start[g], j1 = start[g + 1];
    float inv = (j1 > j0) ? 1.0f / (float)(j1 - j0) : 0.0f;
    for (int c = threadIdx.x; c < D; c += 256) {
        float acc = 0.f;
        for (int n = j0; n < j1; ++n) acc += h[(size_t)n * D + c];
        out[(size_t)g * D + c] = acc * inv;
    }
}

extern "C" void kernel_launch(void* const* d_in, const int* in_sizes, int n_in,
                              void* d_out, int out_size, void* d_ws, size_t ws_size,
                              hipStream_t stream) {
    (void)n_in; (void)ws_size;
    const int*   x     = (const int*)d_in[0];
    const int*   ei    = (const int*)d_in[1];
    const int*   batch = (const int*)d_in[2];
    // d_in[3] = num_hops (fixed 4)
    const float* atomT = (const float*)d_in[4];
    const float* wordT = (const float*)d_in[5];
    const float* W     = (const float*)d_in[6];
    const float* bias  = (const float*)d_in[7];

    const int N = in_sizes[0] / 2;
    const int E = in_sizes[1] / 2;
    const int G = out_size / D;

    const int* src = ei;
    const int* dst = ei + E;

    // workspace layout (fp32 unless noted; all starts 16B-aligned)
    float* fA     = (float*)d_ws;                    // N*D
    float* fB     = fA + (size_t)N * D;              // N*D
    float* dinv   = fB + (size_t)N * D;              // N
    float* csr_w  = dinv + N;                        // E
    float* W2     = csr_w + E;                       // D*D
    float* W4     = W2 + D * D;                      // D*D
    float* w1b    = W4 + D * D;                      // D
    float* w2b    = w1b + D;                         // D
    float* w3b    = w2b + D;                         // D
    float* u0     = w3b + D;                         // N
    float* u1     = u0 + N;                          // N
    float* u2     = u1 + N;                          // N
    float* u3     = u2 + N;                          // N
    short* wtH    = (short*)(u3 + N);                // D*KPAD bf16
    short* wtL    = wtH + (size_t)D * KPAD;          // D*KPAD bf16
    int*   cnt    = (int*)(wtL + (size_t)D * KPAD);  // N
    int*   off    = cnt + N;                         // N+1
    int*   cursor = off + N + 1;                     // N
    int*   csr_src= cursor + N;                      // E
    int*   start  = csr_src + E;                     // G+1

    const int B = 256;
    const int ndBlocks = (N * D4 + B - 1) / B;
    const int nBlocks  = (N + B - 1) / B;

    // h0 (fp32)
    embed_f32<<<ndBlocks, B, 0, stream>>>(x, (const float4*)atomT, (const float4*)wordT, (float4*)fA, N);

    // CSR + segments
    hipMemsetAsync(cnt, 0, (size_t)N * sizeof(int), stream);
    cnt_kernel <<<(E + B - 1) / B, B, 0, stream>>>(dst, cnt, E);
    dinv_kernel<<<nBlocks, B, 0, stream>>>(cnt, dinv, N);
    scan_kernel<<<1, 1024, 0, stream>>>(cnt, off, cursor, N);
    fill_kernel<<<(E + B - 1) / B, B, 0, stream>>>(src, dst, dinv, cursor, csr_src, csr_w, E);
    seg_start_kernel<<<nBlocks, B, 0, stream>>>(batch, start, N, G);

    // u_k = A_hat^k 1
    ones_kernel<<<nBlocks, B, 0, stream>>>(u0, N);
    gather_vec<<<nBlocks, B, 0, stream>>>(u0, off, csr_src, csr_w, dinv, u1, N);
    gather_vec<<<nBlocks, B, 0, stream>>>(u1, off, csr_src, csr_w, dinv, u2, N);
    gather_vec<<<nBlocks, B, 0, stream>>>(u2, off, csr_src, csr_w, dinv, u3, N);

    // W^2, W^4 (fp32, L2-resident), b W^k vectors
    const int sgBlocks = (D * D + B - 1) / B;
    sgemm300<<<sgBlocks, B, 0, stream>>>(W, W, W2);
    sgemm300<<<sgBlocks, B, 0, stream>>>(W2, W2, W4);
    gemv300<<<(D + B - 1) / B, B, 0, stream>>>(bias, W, w1b);
    gemv300<<<(D + B - 1) / B, B, 0, stream>>>(w1b, W, w2b);
    gemv300<<<(D + B - 1) / B, B, 0, stream>>>(w2b, W, w3b);
    wprep_kernel<<<(D * KPAD + B - 1) / B, B, 0, stream>>>(W4, wtH, wtL);

    // g4 = A_hat^4 h0  (ping-pong fA <-> fB)
    gather_f32<<<ndBlocks, B, 0, stream>>>((const float4*)fA, off, csr_src, csr_w, dinv, (float4*)fB, N);
    gather_f32<<<ndBlocks, B, 0, stream>>>((const float4*)fB, off, csr_src, csr_w, dinv, (float4*)fA, N);
    gather_f32<<<ndBlocks, B, 0, stream>>>((const float4*)fA, off, csr_src, csr_w, dinv, (float4*)fB, N);
    gather_f32<<<ndBlocks, B, 0, stream>>>((const float4*)fB, off, csr_src, csr_w, dinv, (float4*)fA, N);

    // h4 = g4 @ W4 + rank-1 bias terms  (fA -> fB)
    const int nmB = (N + BM - 1) / BM;
    const int gemmBlocks = ((nmB + 7) / 8) * 8 * NNB;
    gemm_mfma<<<gemmBlocks, 256, 0, stream>>>(fA, wtH, wtL, u1, u2, u3, w1b, w2b, w3b, bias, fB, N);

    // mean pool
    pool_seg<<<G, B, 0, stream>>>(fB, start, (float*)d_out, G);
}

// Round 11
// 498.903 us; speedup vs baseline: 1.2961x; 1.1859x over previous
//
#include <hip/hip_runtime.h>
#include <hip/hip_bf16.h>
#include <hip/hip_fp16.h>

#define D    300
#define DC   75    // D/4 chunks of 4 elems
#define KPAD 320   // GEMM K padded to 10 k-steps of 32
#define BM   128
#define BN   64
#define LDT  40    // LDS row stride in bf16 (80 B)
#define NNB  5     // n-blocks per m-panel

typedef short bf16x8 __attribute__((ext_vector_type(8)));
typedef float f32x4  __attribute__((ext_vector_type(4)));
typedef _Float16 half4v __attribute__((ext_vector_type(4)));

__device__ inline short f2bh(float f) {            // native cast -> v_cvt_pk_bf16_f32 fusable
    __hip_bfloat16 b = __float2bfloat16(f);
    return *reinterpret_cast<short*>(&b);
}
__device__ inline float bh2f(short s) {
    return __uint_as_float(((unsigned)(unsigned short)s) << 16);
}

// ---------------- embedding -> fp16 h0 ----------------
__global__ __launch_bounds__(256) void embed_f16(const int* __restrict__ x,
                                                 const float4* __restrict__ atomT,
                                                 const float4* __restrict__ wordT,
                                                 half4v* __restrict__ h, int N) {
    int idx = blockIdx.x * blockDim.x + threadIdx.x;
    if (idx >= N * DC) return;
    int n = idx / DC, c = idx % DC;
    int a = x[n * 2 + 0];
    int w = x[n * 2 + 1];
    float4 va = atomT[(size_t)a * DC + c];
    float4 vw = wordT[(size_t)w * DC + c];
    half4v o;
    o[0] = (_Float16)(va.x + vw.x);
    o[1] = (_Float16)(va.y + vw.y);
    o[2] = (_Float16)(va.z + vw.z);
    o[3] = (_Float16)(va.w + vw.w);
    h[idx] = o;
}

// ---------------- CSR build ----------------
__global__ __launch_bounds__(256) void cnt_kernel(const int* __restrict__ dst, int* __restrict__ cnt, int E) {
    int i = blockIdx.x * blockDim.x + threadIdx.x;
    if (i < E) atomicAdd(&cnt[dst[i]], 1);
}
// scan + dinv fused: off/cursor = exclusive scan of cnt; dinv = rsqrt(cnt+1)
__global__ __launch_bounds__(1024) void scan_kernel(const int* __restrict__ cnt,
                                                    int* __restrict__ off, int* __restrict__ cursor,
                                                    float* __restrict__ dinv, int N) {
    __shared__ int warp_sums[16];
    __shared__ int chunk_base;
    const int tid = threadIdx.x;
    const int lane = tid & 63;
    const int wid = tid >> 6;
    if (tid == 0) chunk_base = 0;
    __syncthreads();
    for (int base = 0; base < N; base += 1024) {
        int i = base + tid;
        int v = (i < N) ? cnt[i] : 0;
        if (i < N) dinv[i] = rsqrtf((float)(v + 1));   // +1 self-loop
        int s = v;
        #pragma unroll
        for (int d = 1; d < 64; d <<= 1) {
            int t = __shfl_up(s, d, 64);
            if (lane >= d) s += t;
        }
        if (lane == 63) warp_sums[wid] = s;
        __syncthreads();
        if (wid == 0) {
            int ws = (lane < 16) ? warp_sums[lane] : 0;
            #pragma unroll
            for (int d = 1; d < 16; d <<= 1) {
                int t = __shfl_up(ws, d, 64);
                if (lane >= d) ws += t;
            }
            if (lane < 16) warp_sums[lane] = ws;
        }
        __syncthreads();
        int excl = chunk_base + (wid ? warp_sums[wid - 1] : 0) + s - v;
        if (i < N) { off[i] = excl; cursor[i] = excl; }
        int total = warp_sums[15];
        __syncthreads();
        if (tid == 0) chunk_base += total;
        __syncthreads();
    }
    if (tid == 0) off[N] = chunk_base;
}
__global__ __launch_bounds__(256) void fill_kernel(const int* __restrict__ src, const int* __restrict__ dst,
                                                   const float* __restrict__ dinv, int* __restrict__ cursor,
                                                   int* __restrict__ csr_src, float* __restrict__ csr_w, int E) {
    int e = blockIdx.x * blockDim.x + threadIdx.x;
    if (e >= E) return;
    int s = src[e], d = dst[e];
    int slot = atomicAdd(&cursor[d], 1);
    csr_src[slot] = s;
    csr_w[slot] = dinv[s] * dinv[d];
}
__global__ __launch_bounds__(256) void seg_start_kernel(const int* __restrict__ batch,
                                                        int* __restrict__ start, int N, int G) {
    int i = blockIdx.x * blockDim.x + threadIdx.x;
    if (i >= N) return;
    int b = batch[i];
    int prev = (i == 0) ? -1 : batch[i - 1];
    for (int g = prev + 1; g <= b; ++g) start[g] = i;
    if (i == N - 1)
        for (int g = b + 1; g <= G; ++g) start[g] = N;
}

// ---------------- W-prep, consolidated (3 kernels) ----------------
// K1: W2 = W@W ; w1b = b@W
__global__ __launch_bounds__(256) void wprep1(const float* __restrict__ W, const float* __restrict__ bias,
                                              float* __restrict__ W2, float* __restrict__ w1b) {
    int bid = blockIdx.x;
    if (bid < 352) {
        int id = bid * 256 + threadIdx.x;
        if (id >= D * D) return;
        int i = id / D, j = id % D;
        float acc = 0.f;
        #pragma unroll 4
        for (int k = 0; k < D; ++k) acc = fmaf(W[i * D + k], W[k * D + j], acc);
        W2[id] = acc;
    } else {
        int j = threadIdx.x;
        if (j >= D) return;
        float acc = 0.f;
        #pragma unroll 4
        for (int k = 0; k < D; ++k) acc = fmaf(bias[k], W[k * D + j], acc);
        w1b[j] = acc;
    }
}
// K2: W4 = W2@W2 ; w2b = w1b@W
__global__ __launch_bounds__(256) void wprep2(const float* __restrict__ W2, const float* __restrict__ W,
                                              const float* __restrict__ w1b,
                                              float* __restrict__ W4, float* __restrict__ w2b) {
    int bid = blockIdx.x;
    if (bid < 352) {
        int id = bid * 256 + threadIdx.x;
        if (id >= D * D) return;
        int i = id / D, j = id % D;
        float acc = 0.f;
        #pragma unroll 4
        for (int k = 0; k < D; ++k) acc = fmaf(W2[i * D + k], W2[k * D + j], acc);
        W4[id] = acc;
    } else {
        int j = threadIdx.x;
        if (j >= D) return;
        float acc = 0.f;
        #pragma unroll 4
        for (int k = 0; k < D; ++k) acc = fmaf(w1b[k], W[k * D + j], acc);
        w2b[j] = acc;
    }
}
// K3: wt = split(W4^T, k-padded) ; w3b = w2b@W
__global__ __launch_bounds__(256) void wprep3(const float* __restrict__ W4, const float* __restrict__ W,
                                              const float* __restrict__ w2b,
                                              short* __restrict__ wh, short* __restrict__ wl,
                                              float* __restrict__ w3b) {
    int bid = blockIdx.x;
    if (bid < 375) {
        int id = bid * 256 + threadIdx.x;
        if (id >= D * KPAD) return;
        int n = id / KPAD, k = id % KPAD;
        float v = (k < D) ? W4[(size_t)k * D + n] : 0.f;
        short hh = f2bh(v);
        short ll = f2bh(v - bh2f(hh));
        wh[id] = hh; wl[id] = ll;
    } else {
        int j = threadIdx.x;
        if (j >= D) return;
        float acc = 0.f;
        #pragma unroll 4
        for (int k = 0; k < D; ++k) acc = fmaf(w2b[k], W[k * D + j], acc);
        w3b[j] = acc;
    }
}

// ---------------- sparse hop (fp16 rows), optional fused scalar-u gather ----------------
// out[n,:] = dinv[n]^2*in[n,:] + sum_j w_j in[src_j,:]   (fp32 accum, fp16 store)
// if uout: uout[n] = dinv[n]^2*ui(n) + sum_j w_j ui(src_j), ui = uin or ones.
__global__ __launch_bounds__(256) void gather_f16(const half4v* __restrict__ in,
                                                  const int* __restrict__ off,
                                                  const int* __restrict__ csr_src,
                                                  const float* __restrict__ csr_w,
                                                  const float* __restrict__ dinv,
                                                  const float* __restrict__ uin,
                                                  float* __restrict__ uout,
                                                  half4v* __restrict__ out, int N) {
    int idx = blockIdx.x * blockDim.x + threadIdx.x;
    if (idx >= N * DC) return;
    int n = idx / DC, c = idx - n * DC;
    float s = dinv[n]; s = s * s;
    half4v v0 = in[idx];
    float4 acc = make_float4(s * (float)v0[0], s * (float)v0[1], s * (float)v0[2], s * (float)v0[3]);
    const bool dou = (uout != nullptr) && (c == 0);
    float uacc = 0.f;
    if (dou) uacc = s * (uin ? uin[n] : 1.0f);
    int j0 = off[n], j1 = off[n + 1];
    for (int j = j0; j < j1; ++j) {
        int sn = csr_src[j];
        float w = csr_w[j];
        half4v u = in[(size_t)sn * DC + c];
        acc.x += w * (float)u[0]; acc.y += w * (float)u[1];
        acc.z += w * (float)u[2]; acc.w += w * (float)u[3];
        if (dou) uacc += w * (uin ? uin[sn] : 1.0f);
    }
    half4v o;
    o[0] = (_Float16)acc.x; o[1] = (_Float16)acc.y;
    o[2] = (_Float16)acc.z; o[3] = (_Float16)acc.w;
    out[idx] = o;
    if (dou) uout[n] = uacc;
}

// ---------------- GEMM: C = A(fp16)@W4 + u3*w3b + u2*w2b + u1*w1b + b ----------------
// XCD-swizzled 1D grid: d = q*(8*NNB) + nb*8 + r, mb = q*8 + r.
__global__ __launch_bounds__(256) void gemm_mfma(const _Float16* __restrict__ A,
                                                 const short* __restrict__ WtH,
                                                 const short* __restrict__ WtL,
                                                 const float* __restrict__ u1,
                                                 const float* __restrict__ u2,
                                                 const float* __restrict__ u3,
                                                 const float* __restrict__ w1b,
                                                 const float* __restrict__ w2b,
                                                 const float* __restrict__ w3b,
                                                 const float* __restrict__ bias,
                                                 float* __restrict__ C, int M) {
    const int d_lin = blockIdx.x;
    const int q   = d_lin / (8 * NNB);
    const int rem = d_lin % (8 * NNB);
    const int nb  = rem >> 3;
    const int r   = rem & 7;
    const int mb  = q * 8 + r;
    if (mb * BM >= M) return;
    const int bm = mb * BM;
    const int n0 = nb * BN;

    __shared__ short AsH[BM][LDT], AsL[BM][LDT];
    __shared__ short BsH[BN][LDT], BsL[BN][LDT];

    const int tid = threadIdx.x;
    const int lane = tid & 63, wid = tid >> 6;
    const int g4 = lane >> 4, l16 = lane & 15;
    const int wr0 = wid * 32;

    f32x4 acc[2][4];
    #pragma unroll
    for (int i = 0; i < 2; ++i)
        #pragma unroll
        for (int j = 0; j < 4; ++j) acc[i][j] = (f32x4)0.0f;

    for (int k0 = 0; k0 < KPAD; k0 += 32) {
        // ---- stage A: 128x32 fp16 -> split bf16 (1024 half4 chunks, 4/thread) ----
        #pragma unroll
        for (int i = 0; i < 4; ++i) {
            int g = tid + i * 256;
            int rr = g >> 3, ck = (g & 7) * 4;        // 8 chunks x 4 halves = 32 cols
            int gr = bm + rr, gk = k0 + ck;
            float4 v = make_float4(0.f, 0.f, 0.f, 0.f);
            if (gr < M && gk < D) {                   // gk mult of 4, D mult of 4 -> full chunk
                half4v t = *(const half4v*)&A[(size_t)gr * D + gk];
                v = make_float4((float)t[0], (float)t[1], (float)t[2], (float)t[3]);
            }
            short4 hh, ll;
            hh.x = f2bh(v.x); ll.x = f2bh(v.x - bh2f(hh.x));
            hh.y = f2bh(v.y); ll.y = f2bh(v.y - bh2f(hh.y));
            hh.z = f2bh(v.z); ll.z = f2bh(v.z - bh2f(hh.z));
            hh.w = f2bh(v.w); ll.w = f2bh(v.w - bh2f(hh.w));
            *(short4*)&AsH[rr][ck] = hh;
            *(short4*)&AsL[rr][ck] = ll;
        }
        // ---- stage B: 64x32 bf16 pair (16B chunks) ----
        {
            int g = tid;
            int rr = g >> 2, kc = (g & 3) * 8;
            int gn = n0 + rr;
            bf16x8 vh = (bf16x8)(short)0, vl = (bf16x8)(short)0;
            if (gn < D) {
                vh = *(const bf16x8*)&WtH[(size_t)gn * KPAD + k0 + kc];
                vl = *(const bf16x8*)&WtL[(size_t)gn * KPAD + k0 + kc];
            }
            *(bf16x8*)&BsH[rr][kc] = vh;
            *(bf16x8*)&BsL[rr][kc] = vl;
        }
        __syncthreads();

        bf16x8 ah[2], al[2], bh[4], bl[4];
        #pragma unroll
        for (int mf = 0; mf < 2; ++mf) {
            int row = wr0 + mf * 16 + l16;
            ah[mf] = *(const bf16x8*)&AsH[row][g4 * 8];
            al[mf] = *(const bf16x8*)&AsL[row][g4 * 8];
        }
        #pragma unroll
        for (int nf = 0; nf < 4; ++nf) {
            int col = nf * 16 + l16;
            bh[nf] = *(const bf16x8*)&BsH[col][g4 * 8];
            bl[nf] = *(const bf16x8*)&BsL[col][g4 * 8];
        }
        #pragma unroll
        for (int mf = 0; mf < 2; ++mf)
            #pragma unroll
            for (int nf = 0; nf < 4; ++nf) {
                acc[mf][nf] = __builtin_amdgcn_mfma_f32_16x16x32_bf16(ah[mf], bh[nf], acc[mf][nf], 0, 0, 0);
                acc[mf][nf] = __builtin_amdgcn_mfma_f32_16x16x32_bf16(ah[mf], bl[nf], acc[mf][nf], 0, 0, 0);
                acc[mf][nf] = __builtin_amdgcn_mfma_f32_16x16x32_bf16(al[mf], bh[nf], acc[mf][nf], 0, 0, 0);
            }
        __syncthreads();
    }

    // ---- epilogue: hoisted rank-1 bias terms + C write ----
    float uu1[2][4], uu2[2][4], uu3[2][4];
    #pragma unroll
    for (int mf = 0; mf < 2; ++mf)
        #pragma unroll
        for (int reg = 0; reg < 4; ++reg) {
            int grw = bm + wr0 + mf * 16 + g4 * 4 + reg;
            bool ok = grw < M;
            uu1[mf][reg] = ok ? u1[grw] : 0.f;
            uu2[mf][reg] = ok ? u2[grw] : 0.f;
            uu3[mf][reg] = ok ? u3[grw] : 0.f;
        }
    float cb[4], c1[4], c2[4], c3[4];
    #pragma unroll
    for (int nf = 0; nf < 4; ++nf) {
        int gc = n0 + nf * 16 + l16;
        bool ok = gc < D;
        cb[nf] = ok ? bias[gc] : 0.f;
        c1[nf] = ok ? w1b[gc] : 0.f;
        c2[nf] = ok ? w2b[gc] : 0.f;
        c3[nf] = ok ? w3b[gc] : 0.f;
    }
    #pragma unroll
    for (int mf = 0; mf < 2; ++mf)
        #pragma unroll
        for (int nf = 0; nf < 4; ++nf)
            #pragma unroll
            for (int reg = 0; reg < 4; ++reg) {
                int grow = bm + wr0 + mf * 16 + g4 * 4 + reg;
                int gcol = n0 + nf * 16 + l16;
                if (grow < M && gcol < D) {
                    float v = acc[mf][nf][reg]
                            + uu1[mf][reg] * c1[nf]
                            + uu2[mf][reg] * c2[nf]
                            + uu3[mf][reg] * c3[nf]
                            + cb[nf];
                    C[(size_t)grow * D + gcol] = v;
                }
            }
}

// ---------------- pooling via sorted-batch segments (fp32 C) ----------------
__global__ __launch_bounds__(256) void pool_seg(const float* __restrict__ h,
                                                const int* __restrict__ start,
                                                float* __restrict__ out, int G) {
    int g = blockIdx.x;
    if (g >= G) return;
    int j0 = start[g], j1 = start[g + 1];
    float inv = (j1 > j0) ? 1.0f / (float)(j1 - j0) : 0.0f;
    for (int c = threadIdx.x; c < D; c += 256) {
        float acc = 0.f;
        for (int n = j0; n < j1; ++n) acc += h[(size_t)n * D + c];
        out[(size_t)g * D + c] = acc * inv;
    }
}

extern "C" void kernel_launch(void* const* d_in, const int* in_sizes, int n_in,
                              void* d_out, int out_size, void* d_ws, size_t ws_size,
                              hipStream_t stream) {
    (void)n_in; (void)ws_size;
    const int*   x     = (const int*)d_in[0];
    const int*   ei    = (const int*)d_in[1];
    const int*   batch = (const int*)d_in[2];
    // d_in[3] = num_hops (fixed 4)
    const float* atomT = (const float*)d_in[4];
    const float* wordT = (const float*)d_in[5];
    const float* W     = (const float*)d_in[6];
    const float* bias  = (const float*)d_in[7];

    const int N = in_sizes[0] / 2;
    const int E = in_sizes[1] / 2;
    const int G = out_size / D;

    const int* src = ei;
    const int* dst = ei + E;

    // workspace layout (16B-aligned starts)
    float*    C      = (float*)d_ws;                   // N*D fp32
    _Float16* fA16   = (_Float16*)(C + (size_t)N * D); // N*D fp16
    _Float16* fB16   = fA16 + (size_t)N * D;           // N*D fp16
    float*    dinv   = (float*)(fB16 + (size_t)N * D); // N
    float*    csr_w  = dinv + N;                       // E
    float*    W2     = csr_w + E;                      // D*D
    float*    W4     = W2 + D * D;                     // D*D
    float*    w1b    = W4 + D * D;                     // D
    float*    w2b    = w1b + D;                        // D
    float*    w3b    = w2b + D;                        // D
    float*    u1     = w3b + D;                        // N
    float*    u2     = u1 + N;                         // N
    float*    u3     = u2 + N;                         // N
    short*    wtH    = (short*)(u3 + N);               // D*KPAD bf16
    short*    wtL    = wtH + (size_t)D * KPAD;         // D*KPAD bf16
    int*      cnt    = (int*)(wtL + (size_t)D * KPAD); // N
    int*      off    = cnt + N;                        // N+1
    int*      cursor = off + N + 1;                    // N
    int*      csr_src= cursor + N;                     // E
    int*      start  = csr_src + E;                    // G+1

    const int B = 256;
    const int ndBlocks = (N * DC + B - 1) / B;
    const int nBlocks  = (N + B - 1) / B;

    embed_f16<<<ndBlocks, B, 0, stream>>>(x, (const float4*)atomT, (const float4*)wordT, (half4v*)fA16, N);

    hipMemsetAsync(cnt, 0, (size_t)N * sizeof(int), stream);
    cnt_kernel<<<(E + B - 1) / B, B, 0, stream>>>(dst, cnt, E);
    scan_kernel<<<1, 1024, 0, stream>>>(cnt, off, cursor, dinv, N);
    fill_kernel<<<(E + B - 1) / B, B, 0, stream>>>(src, dst, dinv, cursor, csr_src, csr_w, E);
    seg_start_kernel<<<nBlocks, B, 0, stream>>>(batch, start, N, G);

    wprep1<<<353, B, 0, stream>>>(W, bias, W2, w1b);
    wprep2<<<353, B, 0, stream>>>(W2, W, w1b, W4, w2b);
    wprep3<<<376, B, 0, stream>>>(W4, W, w2b, wtH, wtL, w3b);

    // g_k = A_hat^k h0 (fp16 ping-pong), u_k fused into passes 1-3
    gather_f16<<<ndBlocks, B, 0, stream>>>((const half4v*)fA16, off, csr_src, csr_w, dinv,
                                           nullptr, u1, (half4v*)fB16, N);
    gather_f16<<<ndBlocks, B, 0, stream>>>((const half4v*)fB16, off, csr_src, csr_w, dinv,
                                           u1, u2, (half4v*)fA16, N);
    gather_f16<<<ndBlocks, B, 0, stream>>>((const half4v*)fA16, off, csr_src, csr_w, dinv,
                                           u2, u3, (half4v*)fB16, N);
    gather_f16<<<ndBlocks, B, 0, stream>>>((const half4v*)fB16, off, csr_src, csr_w, dinv,
                                           nullptr, nullptr, (half4v*)fA16, N);

    // h4 = g4 @ W4 + rank-1 bias terms
    const int nmB = (N + BM - 1) / BM;
    const int gemmBlocks = ((nmB + 7) / 8) * 8 * NNB;
    gemm_mfma<<<gemmBlocks, 256, 0, stream>>>(fA16, wtH, wtL, u1, u2, u3, w1b, w2b, w3b, bias, C, N);

    pool_seg<<<G, B, 0, stream>>>(C, start, (float*)d_out, G);
}

// Round 12
// 492.754 us; speedup vs baseline: 1.3123x; 1.0125x over previous
//
#include <hip/hip_runtime.h>
#include <hip/hip_bf16.h>
#include <hip/hip_fp16.h>

#define D    300
#define DC   75    // D/4 half4 chunks (valid data)
#define KPAD 320   // k-padded row length for h (fp16) and Wt
#define KC   80    // KPAD/4 half4 chunks
#define BM   128
#define BN   64
#define BK   64
#define LDT  72    // LDS row stride in fp16 elems (144 B = 9*16, bank-spread)
#define NNB  5     // n-blocks per m-panel
#define LSCALE 2048.0f   // 2^11 scale for W low half (avoids fp16 subnormals)

typedef _Float16 f16x8 __attribute__((ext_vector_type(8)));
typedef _Float16 half4v __attribute__((ext_vector_type(4)));
typedef float f32x4  __attribute__((ext_vector_type(4)));

// ---------------- embedding -> fp16 h0, k-padded ----------------
__global__ __launch_bounds__(256) void embed_f16(const int* __restrict__ x,
                                                 const float4* __restrict__ atomT,
                                                 const float4* __restrict__ wordT,
                                                 half4v* __restrict__ h, int N) {
    int idx = blockIdx.x * blockDim.x + threadIdx.x;
    if (idx >= N * KC) return;
    int n = idx / KC, c = idx - n * KC;
    if (c >= DC) { h[idx] = (half4v)(_Float16)0; return; }   // zero k-pad
    int a = x[n * 2 + 0];
    int w = x[n * 2 + 1];
    float4 va = atomT[(size_t)a * DC + c];
    float4 vw = wordT[(size_t)w * DC + c];
    half4v o;
    o[0] = (_Float16)(va.x + vw.x);
    o[1] = (_Float16)(va.y + vw.y);
    o[2] = (_Float16)(va.z + vw.z);
    o[3] = (_Float16)(va.w + vw.w);
    h[idx] = o;
}

// ---------------- CSR build ----------------
__global__ __launch_bounds__(256) void cnt_kernel(const int* __restrict__ dst, int* __restrict__ cnt, int E) {
    int i = blockIdx.x * blockDim.x + threadIdx.x;
    if (i < E) atomicAdd(&cnt[dst[i]], 1);
}
// scan + dinv fused
__global__ __launch_bounds__(1024) void scan_kernel(const int* __restrict__ cnt,
                                                    int* __restrict__ off, int* __restrict__ cursor,
                                                    float* __restrict__ dinv, int N) {
    __shared__ int warp_sums[16];
    __shared__ int chunk_base;
    const int tid = threadIdx.x;
    const int lane = tid & 63;
    const int wid = tid >> 6;
    if (tid == 0) chunk_base = 0;
    __syncthreads();
    for (int base = 0; base < N; base += 1024) {
        int i = base + tid;
        int v = (i < N) ? cnt[i] : 0;
        if (i < N) dinv[i] = rsqrtf((float)(v + 1));   // +1 self-loop
        int s = v;
        #pragma unroll
        for (int d = 1; d < 64; d <<= 1) {
            int t = __shfl_up(s, d, 64);
            if (lane >= d) s += t;
        }
        if (lane == 63) warp_sums[wid] = s;
        __syncthreads();
        if (wid == 0) {
            int ws = (lane < 16) ? warp_sums[lane] : 0;
            #pragma unroll
            for (int d = 1; d < 16; d <<= 1) {
                int t = __shfl_up(ws, d, 64);
                if (lane >= d) ws += t;
            }
            if (lane < 16) warp_sums[lane] = ws;
        }
        __syncthreads();
        int excl = chunk_base + (wid ? warp_sums[wid - 1] : 0) + s - v;
        if (i < N) { off[i] = excl; cursor[i] = excl; }
        int total = warp_sums[15];
        __syncthreads();
        if (tid == 0) chunk_base += total;
        __syncthreads();
    }
    if (tid == 0) off[N] = chunk_base;
}
__global__ __launch_bounds__(256) void fill_kernel(const int* __restrict__ src, const int* __restrict__ dst,
                                                   const float* __restrict__ dinv, int* __restrict__ cursor,
                                                   int* __restrict__ csr_src, float* __restrict__ csr_w, int E) {
    int e = blockIdx.x * blockDim.x + threadIdx.x;
    if (e >= E) return;
    int s = src[e], d = dst[e];
    int slot = atomicAdd(&cursor[d], 1);
    csr_src[slot] = s;
    csr_w[slot] = dinv[s] * dinv[d];
}
__global__ __launch_bounds__(256) void seg_start_kernel(const int* __restrict__ batch,
                                                        int* __restrict__ start, int N, int G) {
    int i = blockIdx.x * blockDim.x + threadIdx.x;
    if (i >= N) return;
    int b = batch[i];
    int prev = (i == 0) ? -1 : batch[i - 1];
    for (int g = prev + 1; g <= b; ++g) start[g] = i;
    if (i == N - 1)
        for (int g = b + 1; g <= G; ++g) start[g] = N;
}

// ---------------- W-prep (3 kernels) ----------------
__global__ __launch_bounds__(256) void wprep1(const float* __restrict__ W, const float* __restrict__ bias,
                                              float* __restrict__ W2, float* __restrict__ w1b) {
    int bid = blockIdx.x;
    if (bid < 352) {
        int id = bid * 256 + threadIdx.x;
        if (id >= D * D) return;
        int i = id / D, j = id % D;
        float acc = 0.f;
        #pragma unroll 4
        for (int k = 0; k < D; ++k) acc = fmaf(W[i * D + k], W[k * D + j], acc);
        W2[id] = acc;
    } else {
        int j = threadIdx.x;
        if (j >= D) return;
        float acc = 0.f;
        #pragma unroll 4
        for (int k = 0; k < D; ++k) acc = fmaf(bias[k], W[k * D + j], acc);
        w1b[j] = acc;
    }
}
__global__ __launch_bounds__(256) void wprep2(const float* __restrict__ W2, const float* __restrict__ W,
                                              const float* __restrict__ w1b,
                                              float* __restrict__ W4, float* __restrict__ w2b) {
    int bid = blockIdx.x;
    if (bid < 352) {
        int id = bid * 256 + threadIdx.x;
        if (id >= D * D) return;
        int i = id / D, j = id % D;
        float acc = 0.f;
        #pragma unroll 4
        for (int k = 0; k < D; ++k) acc = fmaf(W2[i * D + k], W2[k * D + j], acc);
        W4[id] = acc;
    } else {
        int j = threadIdx.x;
        if (j >= D) return;
        float acc = 0.f;
        #pragma unroll 4
        for (int k = 0; k < D; ++k) acc = fmaf(w1b[k], W[k * D + j], acc);
        w2b[j] = acc;
    }
}
// K3: Wt = split-fp16(W4^T, k-padded), low scaled by 2^11 ; w3b = w2b@W
__global__ __launch_bounds__(256) void wprep3(const float* __restrict__ W4, const float* __restrict__ W,
                                              const float* __restrict__ w2b,
                                              _Float16* __restrict__ wh, _Float16* __restrict__ wl,
                                              float* __restrict__ w3b) {
    int bid = blockIdx.x;
    if (bid < 375) {
        int id = bid * 256 + threadIdx.x;
        if (id >= D * KPAD) return;
        int n = id / KPAD, k = id % KPAD;
        float v = (k < D) ? W4[(size_t)k * D + n] : 0.f;
        _Float16 hh = (_Float16)v;
        _Float16 ll = (_Float16)((v - (float)hh) * LSCALE);
        wh[id] = hh; wl[id] = ll;
    } else {
        int j = threadIdx.x;
        if (j >= D) return;
        float acc = 0.f;
        #pragma unroll 4
        for (int k = 0; k < D; ++k) acc = fmaf(w2b[k], W[k * D + j], acc);
        w3b[j] = acc;
    }
}

// ---------------- sparse hop (fp16 rows, k-padded), optional fused scalar-u ----------------
__global__ __launch_bounds__(256) void gather_f16(const half4v* __restrict__ in,
                                                  const int* __restrict__ off,
                                                  const int* __restrict__ csr_src,
                                                  const float* __restrict__ csr_w,
                                                  const float* __restrict__ dinv,
                                                  const float* __restrict__ uin,
                                                  float* __restrict__ uout,
                                                  half4v* __restrict__ out, int N) {
    int idx = blockIdx.x * blockDim.x + threadIdx.x;
    if (idx >= N * KC) return;
    int n = idx / KC, c = idx - n * KC;
    if (c >= DC) { out[idx] = (half4v)(_Float16)0; return; }   // keep k-pad zero
    float s = dinv[n]; s = s * s;
    half4v v0 = in[idx];
    float4 acc = make_float4(s * (float)v0[0], s * (float)v0[1], s * (float)v0[2], s * (float)v0[3]);
    const bool dou = (uout != nullptr) && (c == 0);
    float uacc = 0.f;
    if (dou) uacc = s * (uin ? uin[n] : 1.0f);
    int j0 = off[n], j1 = off[n + 1];
    for (int j = j0; j < j1; ++j) {
        int sn = csr_src[j];
        float w = csr_w[j];
        half4v u = in[(size_t)sn * KC + c];
        acc.x += w * (float)u[0]; acc.y += w * (float)u[1];
        acc.z += w * (float)u[2]; acc.w += w * (float)u[3];
        if (dou) uacc += w * (uin ? uin[sn] : 1.0f);
    }
    half4v o;
    o[0] = (_Float16)acc.x; o[1] = (_Float16)acc.y;
    o[2] = (_Float16)acc.z; o[3] = (_Float16)acc.w;
    out[idx] = o;
    if (dou) uout[n] = uacc;
}

// ---------------- GEMM: C = A(fp16,[M][KPAD]) @ W4 + rank-1 bias terms ----------------
// split-fp16 2-pass f16 MFMA: acc = A@Wh + (A@Wl')/2^11, Wl' = (W4-Wh)*2^11.
// XCD-swizzled 1D grid: d = q*(8*NNB) + nb*8 + r, mb = q*8 + r.
__global__ __launch_bounds__(256) void gemm_mfma(const _Float16* __restrict__ A,
                                                 const _Float16* __restrict__ WtH,
                                                 const _Float16* __restrict__ WtL,
                                                 const float* __restrict__ u1,
                                                 const float* __restrict__ u2,
                                                 const float* __restrict__ u3,
                                                 const float* __restrict__ w1b,
                                                 const float* __restrict__ w2b,
                                                 const float* __restrict__ w3b,
                                                 const float* __restrict__ bias,
                                                 float* __restrict__ C, int M) {
    const int d_lin = blockIdx.x;
    const int q   = d_lin / (8 * NNB);
    const int rem = d_lin % (8 * NNB);
    const int nb  = rem >> 3;
    const int r   = rem & 7;
    const int mb  = q * 8 + r;
    if (mb * BM >= M) return;
    const int bm = mb * BM;
    const int n0 = nb * BN;

    __shared__ _Float16 As[BM][LDT];                 // 18.4 KB
    __shared__ _Float16 BsH[BN][LDT], BsL[BN][LDT];  // 9.2 + 9.2 KB

    const int tid = threadIdx.x;
    const int lane = tid & 63, wid = tid >> 6;
    const int g4 = lane >> 4, l16 = lane & 15;
    const int wr0 = wid * 32;

    f32x4 accH[2][4], accL[2][4];
    #pragma unroll
    for (int i = 0; i < 2; ++i)
        #pragma unroll
        for (int j = 0; j < 4; ++j) { accH[i][j] = (f32x4)0.0f; accL[i][j] = (f32x4)0.0f; }

    for (int k0 = 0; k0 < KPAD; k0 += BK) {
        // ---- stage A: 128x64 fp16, 1024 16B chunks, 4/thread ----
        #pragma unroll
        for (int i = 0; i < 4; ++i) {
            int g = tid + i * 256;
            int rr = g >> 3, ck = (g & 7) * 8;
            int gr = bm + rr;
            f16x8 v = (f16x8)(_Float16)0;
            if (gr < M) v = *(const f16x8*)&A[(size_t)gr * KPAD + k0 + ck];
            *(f16x8*)&As[rr][ck] = v;
        }
        // ---- stage B: 64x64 fp16 pair, 512 chunks each, 2/thread each ----
        #pragma unroll
        for (int i = 0; i < 2; ++i) {
            int g = tid + i * 256;
            int rr = g >> 3, kc = (g & 7) * 8;
            int gn = n0 + rr;
            f16x8 vh = (f16x8)(_Float16)0, vl = (f16x8)(_Float16)0;
            if (gn < D) {
                vh = *(const f16x8*)&WtH[(size_t)gn * KPAD + k0 + kc];
                vl = *(const f16x8*)&WtL[(size_t)gn * KPAD + k0 + kc];
            }
            *(f16x8*)&BsH[rr][kc] = vh;
            *(f16x8*)&BsL[rr][kc] = vl;
        }
        __syncthreads();

        #pragma unroll
        for (int s = 0; s < 2; ++s) {
            f16x8 a[2], bh[4], bl[4];
            #pragma unroll
            for (int mf = 0; mf < 2; ++mf) {
                int row = wr0 + mf * 16 + l16;
                a[mf] = *(const f16x8*)&As[row][s * 32 + g4 * 8];
            }
            #pragma unroll
            for (int nf = 0; nf < 4; ++nf) {
                int col = nf * 16 + l16;
                bh[nf] = *(const f16x8*)&BsH[col][s * 32 + g4 * 8];
                bl[nf] = *(const f16x8*)&BsL[col][s * 32 + g4 * 8];
            }
            #pragma unroll
            for (int mf = 0; mf < 2; ++mf)
                #pragma unroll
                for (int nf = 0; nf < 4; ++nf) {
                    accH[mf][nf] = __builtin_amdgcn_mfma_f32_16x16x32_f16(a[mf], bh[nf], accH[mf][nf], 0, 0, 0);
                    accL[mf][nf] = __builtin_amdgcn_mfma_f32_16x16x32_f16(a[mf], bl[nf], accL[mf][nf], 0, 0, 0);
                }
        }
        __syncthreads();
    }

    // ---- epilogue: accH + accL/2^11 + rank-1 bias terms ----
    float uu1[2][4], uu2[2][4], uu3[2][4];
    #pragma unroll
    for (int mf = 0; mf < 2; ++mf)
        #pragma unroll
        for (int reg = 0; reg < 4; ++reg) {
            int grw = bm + wr0 + mf * 16 + g4 * 4 + reg;
            bool ok = grw < M;
            uu1[mf][reg] = ok ? u1[grw] : 0.f;
            uu2[mf][reg] = ok ? u2[grw] : 0.f;
            uu3[mf][reg] = ok ? u3[grw] : 0.f;
        }
    float cb[4], c1[4], c2[4], c3[4];
    #pragma unroll
    for (int nf = 0; nf < 4; ++nf) {
        int gc = n0 + nf * 16 + l16;
        bool ok = gc < D;
        cb[nf] = ok ? bias[gc] : 0.f;
        c1[nf] = ok ? w1b[gc] : 0.f;
        c2[nf] = ok ? w2b[gc] : 0.f;
        c3[nf] = ok ? w3b[gc] : 0.f;
    }
    const float inv_ls = 1.0f / LSCALE;
    #pragma unroll
    for (int mf = 0; mf < 2; ++mf)
        #pragma unroll
        for (int nf = 0; nf < 4; ++nf)
            #pragma unroll
            for (int reg = 0; reg < 4; ++reg) {
                int grow = bm + wr0 + mf * 16 + g4 * 4 + reg;
                int gcol = n0 + nf * 16 + l16;
                if (grow < M && gcol < D) {
                    float v = accH[mf][nf][reg] + accL[mf][nf][reg] * inv_ls
                            + uu1[mf][reg] * c1[nf]
                            + uu2[mf][reg] * c2[nf]
                            + uu3[mf][reg] * c3[nf]
                            + cb[nf];
                    C[(size_t)grow * D + gcol] = v;
                }
            }
}

// ---------------- pooling via sorted-batch segments (fp32 C) ----------------
__global__ __launch_bounds__(256) void pool_seg(const float* __restrict__ h,
                                                const int* __restrict__ start,
                                                float* __restrict__ out, int G) {
    int g = blockIdx.x;
    if (g >= G) return;
    int j0 = start[g], j1 = start[g + 1];
    float inv = (j1 > j0) ? 1.0f / (float)(j1 - j0) : 0.0f;
    for (int c = threadIdx.x; c < D; c += 256) {
        float acc = 0.f;
        for (int n = j0; n < j1; ++n) acc += h[(size_t)n * D + c];
        out[(size_t)g * D + c] = acc * inv;
    }
}

extern "C" void kernel_launch(void* const* d_in, const int* in_sizes, int n_in,
                              void* d_out, int out_size, void* d_ws, size_t ws_size,
                              hipStream_t stream) {
    (void)n_in; (void)ws_size;
    const int*   x     = (const int*)d_in[0];
    const int*   ei    = (const int*)d_in[1];
    const int*   batch = (const int*)d_in[2];
    // d_in[3] = num_hops (fixed 4)
    const float* atomT = (const float*)d_in[4];
    const float* wordT = (const float*)d_in[5];
    const float* W     = (const float*)d_in[6];
    const float* bias  = (const float*)d_in[7];

    const int N = in_sizes[0] / 2;
    const int E = in_sizes[1] / 2;
    const int G = out_size / D;

    const int* src = ei;
    const int* dst = ei + E;

    // workspace layout (16B-aligned starts)
    float*    C      = (float*)d_ws;                     // N*D fp32
    _Float16* fA16   = (_Float16*)(C + (size_t)N * D);   // N*KPAD fp16
    _Float16* fB16   = fA16 + (size_t)N * KPAD;          // N*KPAD fp16
    float*    dinv   = (float*)(fB16 + (size_t)N * KPAD);// N
    float*    csr_w  = dinv + N;                         // E
    float*    W2     = csr_w + E;                        // D*D
    float*    W4     = W2 + D * D;                       // D*D
    float*    w1b    = W4 + D * D;                       // D
    float*    w2b    = w1b + D;                          // D
    float*    w3b    = w2b + D;                          // D
    float*    u1     = w3b + D;                          // N
    float*    u2     = u1 + N;                           // N
    float*    u3     = u2 + N;                           // N
    _Float16* wtH    = (_Float16*)(u3 + N);              // D*KPAD fp16
    _Float16* wtL    = wtH + (size_t)D * KPAD;           // D*KPAD fp16
    int*      cnt    = (int*)(wtL + (size_t)D * KPAD);   // N
    int*      off    = cnt + N;                          // N+1
    int*      cursor = off + N + 1;                      // N
    int*      csr_src= cursor + N;                       // E
    int*      start  = csr_src + E;                      // G+1

    const int B = 256;
    const int ndBlocks = (N * KC + B - 1) / B;
    const int nBlocks  = (N + B - 1) / B;

    embed_f16<<<ndBlocks, B, 0, stream>>>(x, (const float4*)atomT, (const float4*)wordT, (half4v*)fA16, N);

    hipMemsetAsync(cnt, 0, (size_t)N * sizeof(int), stream);
    cnt_kernel<<<(E + B - 1) / B, B, 0, stream>>>(dst, cnt, E);
    scan_kernel<<<1, 1024, 0, stream>>>(cnt, off, cursor, dinv, N);
    fill_kernel<<<(E + B - 1) / B, B, 0, stream>>>(src, dst, dinv, cursor, csr_src, csr_w, E);
    seg_start_kernel<<<nBlocks, B, 0, stream>>>(batch, start, N, G);

    wprep1<<<353, B, 0, stream>>>(W, bias, W2, w1b);
    wprep2<<<353, B, 0, stream>>>(W2, W, w1b, W4, w2b);
    wprep3<<<376, B, 0, stream>>>(W4, W, w2b, wtH, wtL, w3b);

    // g_k = A_hat^k h0 (fp16 ping-pong), u_k fused into passes 1-3
    gather_f16<<<ndBlocks, B, 0, stream>>>((const half4v*)fA16, off, csr_src, csr_w, dinv,
                                           nullptr, u1, (half4v*)fB16, N);
    gather_f16<<<ndBlocks, B, 0, stream>>>((const half4v*)fB16, off, csr_src, csr_w, dinv,
                                           u1, u2, (half4v*)fA16, N);
    gather_f16<<<ndBlocks, B, 0, stream>>>((const half4v*)fA16, off, csr_src, csr_w, dinv,
                                           u2, u3, (half4v*)fB16, N);
    gather_f16<<<ndBlocks, B, 0, stream>>>((const half4v*)fB16, off, csr_src, csr_w, dinv,
                                           nullptr, nullptr, (half4v*)fA16, N);

    // h4 = g4 @ W4 + rank-1 bias terms
    const int nmB = (N + BM - 1) / BM;
    const int gemmBlocks = ((nmB + 7) / 8) * 8 * NNB;
    gemm_mfma<<<gemmBlocks, 256, 0, stream>>>(fA16, wtH, wtL, u1, u2, u3, w1b, w2b, w3b, bias, C, N);

    pool_seg<<<G, B, 0, stream>>>(C, start, (float*)d_out, G);
}

// Round 13
// 437.240 us; speedup vs baseline: 1.4789x; 1.1270x over previous
//
#include <hip/hip_runtime.h>
#include <hip/hip_fp16.h>

#define D    300
#define DC   75    // D/4 half4 chunks per row
#define NNB  5

typedef _Float16 half4v __attribute__((ext_vector_type(4)));

// ---------------- embedding -> fp16 h0 (compact N x D) ----------------
__global__ __launch_bounds__(256) void embed_f16(const int* __restrict__ x,
                                                 const float4* __restrict__ atomT,
                                                 const float4* __restrict__ wordT,
                                                 half4v* __restrict__ h, int N) {
    int idx = blockIdx.x * blockDim.x + threadIdx.x;
    if (idx >= N * DC) return;
    int n = idx / DC, c = idx - n * DC;
    int a = x[n * 2 + 0];
    int w = x[n * 2 + 1];
    float4 va = atomT[(size_t)a * DC + c];
    float4 vw = wordT[(size_t)w * DC + c];
    half4v o;
    o[0] = (_Float16)(va.x + vw.x);
    o[1] = (_Float16)(va.y + vw.y);
    o[2] = (_Float16)(va.z + vw.z);
    o[3] = (_Float16)(va.w + vw.w);
    h[idx] = o;
}

// ---------------- CSR build ----------------
__global__ __launch_bounds__(256) void cnt_kernel(const int* __restrict__ dst, int* __restrict__ cnt, int E) {
    int i = blockIdx.x * blockDim.x + threadIdx.x;
    if (i < E) atomicAdd(&cnt[dst[i]], 1);
}
// scan + dinv fused
__global__ __launch_bounds__(1024) void scan_kernel(const int* __restrict__ cnt,
                                                    int* __restrict__ off, int* __restrict__ cursor,
                                                    float* __restrict__ dinv, int N) {
    __shared__ int warp_sums[16];
    __shared__ int chunk_base;
    const int tid = threadIdx.x;
    const int lane = tid & 63;
    const int wid = tid >> 6;
    if (tid == 0) chunk_base = 0;
    __syncthreads();
    for (int base = 0; base < N; base += 1024) {
        int i = base + tid;
        int v = (i < N) ? cnt[i] : 0;
        if (i < N) dinv[i] = rsqrtf((float)(v + 1));   // +1 self-loop
        int s = v;
        #pragma unroll
        for (int d = 1; d < 64; d <<= 1) {
            int t = __shfl_up(s, d, 64);
            if (lane >= d) s += t;
        }
        if (lane == 63) warp_sums[wid] = s;
        __syncthreads();
        if (wid == 0) {
            int ws = (lane < 16) ? warp_sums[lane] : 0;
            #pragma unroll
            for (int d = 1; d < 16; d <<= 1) {
                int t = __shfl_up(ws, d, 64);
                if (lane >= d) ws += t;
            }
            if (lane < 16) warp_sums[lane] = ws;
        }
        __syncthreads();
        int excl = chunk_base + (wid ? warp_sums[wid - 1] : 0) + s - v;
        if (i < N) { off[i] = excl; cursor[i] = excl; }
        int total = warp_sums[15];
        __syncthreads();
        if (tid == 0) chunk_base += total;
        __syncthreads();
    }
    if (tid == 0) off[N] = chunk_base;
}
__global__ __launch_bounds__(256) void fill_kernel(const int* __restrict__ src, const int* __restrict__ dst,
                                                   const float* __restrict__ dinv, int* __restrict__ cursor,
                                                   int* __restrict__ csr_src, float* __restrict__ csr_w, int E) {
    int e = blockIdx.x * blockDim.x + threadIdx.x;
    if (e >= E) return;
    int s = src[e], d = dst[e];
    int slot = atomicAdd(&cursor[d], 1);
    csr_src[slot] = s;
    csr_w[slot] = dinv[s] * dinv[d];
}
__global__ __launch_bounds__(256) void seg_start_kernel(const int* __restrict__ batch,
                                                        int* __restrict__ start, int N, int G) {
    int i = blockIdx.x * blockDim.x + threadIdx.x;
    if (i >= N) return;
    int b = batch[i];
    int prev = (i == 0) ? -1 : batch[i - 1];
    for (int g = prev + 1; g <= b; ++g) start[g] = i;
    if (i == N - 1)
        for (int g = b + 1; g <= G; ++g) start[g] = N;
}

// ---------------- W-prep (2 kernels, all fp32) ----------------
// K1: W2 = W@W ; w1b = b@W
__global__ __launch_bounds__(256) void wprep1(const float* __restrict__ W, const float* __restrict__ bias,
                                              float* __restrict__ W2, float* __restrict__ w1b) {
    int bid = blockIdx.x;
    if (bid < 352) {
        int id = bid * 256 + threadIdx.x;
        if (id >= D * D) return;
        int i = id / D, j = id % D;
        float acc = 0.f;
        #pragma unroll 4
        for (int k = 0; k < D; ++k) acc = fmaf(W[i * D + k], W[k * D + j], acc);
        W2[id] = acc;
    } else {
        int j = threadIdx.x;
        if (j >= D) return;
        float acc = 0.f;
        #pragma unroll 4
        for (int k = 0; k < D; ++k) acc = fmaf(bias[k], W[k * D + j], acc);
        w1b[j] = acc;
    }
}
// K2: W4 = W2@W2 ; w2b = w1b@W ; w3b = w1b@W2
__global__ __launch_bounds__(256) void wprep2(const float* __restrict__ W2, const float* __restrict__ W,
                                              const float* __restrict__ w1b,
                                              float* __restrict__ W4, float* __restrict__ w2b,
                                              float* __restrict__ w3b) {
    int bid = blockIdx.x;
    if (bid < 352) {
        int id = bid * 256 + threadIdx.x;
        if (id >= D * D) return;
        int i = id / D, j = id % D;
        float acc = 0.f;
        #pragma unroll 4
        for (int k = 0; k < D; ++k) acc = fmaf(W2[i * D + k], W2[k * D + j], acc);
        W4[id] = acc;
    } else if (bid == 352) {
        int j = threadIdx.x;
        if (j >= D) return;
        float acc = 0.f;
        #pragma unroll 4
        for (int k = 0; k < D; ++k) acc = fmaf(w1b[k], W[k * D + j], acc);
        w2b[j] = acc;
    } else {
        int j = threadIdx.x;
        if (j >= D) return;
        float acc = 0.f;
        #pragma unroll 4
        for (int k = 0; k < D; ++k) acc = fmaf(w1b[k], W2[k * D + j], acc);
        w3b[j] = acc;
    }
}

// ---------------- sparse hop (fp16 rows, compact), optional fused scalar-u ----------------
__global__ __launch_bounds__(256) void gather_f16(const half4v* __restrict__ in,
                                                  const int* __restrict__ off,
                                                  const int* __restrict__ csr_src,
                                                  const float* __restrict__ csr_w,
                                                  const float* __restrict__ dinv,
                                                  const float* __restrict__ uin,
                                                  float* __restrict__ uout,
                                                  half4v* __restrict__ out, int N) {
    int idx = blockIdx.x * blockDim.x + threadIdx.x;
    if (idx >= N * DC) return;
    int n = idx / DC, c = idx - n * DC;
    float s = dinv[n]; s = s * s;
    half4v v0 = in[idx];
    float4 acc = make_float4(s * (float)v0[0], s * (float)v0[1], s * (float)v0[2], s * (float)v0[3]);
    const bool dou = (uout != nullptr) && (c == 0);
    float uacc = 0.f;
    if (dou) uacc = s * (uin ? uin[n] : 1.0f);
    int j0 = off[n], j1 = off[n + 1];
    for (int j = j0; j < j1; ++j) {
        int sn = csr_src[j];
        float w = csr_w[j];
        half4v u = in[(size_t)sn * DC + c];
        acc.x += w * (float)u[0]; acc.y += w * (float)u[1];
        acc.z += w * (float)u[2]; acc.w += w * (float)u[3];
        if (dou) uacc += w * (uin ? uin[sn] : 1.0f);
    }
    half4v o;
    o[0] = (_Float16)acc.x; o[1] = (_Float16)acc.y;
    o[2] = (_Float16)acc.z; o[3] = (_Float16)acc.w;
    out[idx] = o;
    if (dou) uout[n] = uacc;
}

// ---------------- pool g4 + u's per graph (segment means) ----------------
// pg4[g][0..D) = mean of g4 rows; pu[g*4+{0,1,2}] = mean u1/u2/u3; pu[g*4+3] = 1 if non-empty.
__global__ __launch_bounds__(256) void pool_seg(const half4v* __restrict__ g4,
                                                const float* __restrict__ u1,
                                                const float* __restrict__ u2,
                                                const float* __restrict__ u3,
                                                const int* __restrict__ start,
                                                float* __restrict__ pg4, float* __restrict__ pu, int G) {
    int g = blockIdx.x;
    if (g >= G) return;
    int j0 = start[g], j1 = start[g + 1];
    float inv = (j1 > j0) ? 1.0f / (float)(j1 - j0) : 0.0f;
    int tid = threadIdx.x;
    if (tid < DC) {
        float4 acc = make_float4(0.f, 0.f, 0.f, 0.f);
        for (int n = j0; n < j1; ++n) {
            half4v v = g4[(size_t)n * DC + tid];
            acc.x += (float)v[0]; acc.y += (float)v[1];
            acc.z += (float)v[2]; acc.w += (float)v[3];
        }
        float4 o = make_float4(acc.x * inv, acc.y * inv, acc.z * inv, acc.w * inv);
        *(float4*)&pg4[(size_t)g * D + tid * 4] = o;
    } else if (tid == DC || tid == DC + 1 || tid == DC + 2) {
        const float* u = (tid == DC) ? u1 : (tid == DC + 1) ? u2 : u3;
        float acc = 0.f;
        for (int n = j0; n < j1; ++n) acc += u[n];
        pu[g * 4 + (tid - DC)] = acc * inv;
    } else if (tid == DC + 3) {
        pu[g * 4 + 3] = (j1 > j0) ? 1.0f : 0.0f;
    }
}

// ---------------- final small GEMM (fp32, exact): out = pg4@W4 + rank-1 terms ----------------
__global__ __launch_bounds__(256) void final_small(const float* __restrict__ pg4,
                                                   const float* __restrict__ pu,
                                                   const float* __restrict__ W4,
                                                   const float* __restrict__ w1b,
                                                   const float* __restrict__ w2b,
                                                   const float* __restrict__ w3b,
                                                   const float* __restrict__ bias,
                                                   float* __restrict__ out, int G) {
    __shared__ float row[D];
    int g = blockIdx.x;
    if (g >= G) return;
    int tid = threadIdx.x;
    for (int c = tid; c < D; c += 256) row[c] = pg4[(size_t)g * D + c];
    __syncthreads();
    float p1 = pu[g * 4 + 0], p2 = pu[g * 4 + 1], p3 = pu[g * 4 + 2], fl = pu[g * 4 + 3];
    for (int j = tid; j < D; j += 256) {
        float acc = 0.f;
        #pragma unroll 4
        for (int k = 0; k < D; ++k) acc = fmaf(row[k], W4[(size_t)k * D + j], acc);
        out[(size_t)g * D + j] = acc + p1 * w1b[j] + p2 * w2b[j] + p3 * w3b[j] + fl * bias[j];
    }
}

extern "C" void kernel_launch(void* const* d_in, const int* in_sizes, int n_in,
                              void* d_out, int out_size, void* d_ws, size_t ws_size,
                              hipStream_t stream) {
    (void)n_in; (void)ws_size;
    const int*   x     = (const int*)d_in[0];
    const int*   ei    = (const int*)d_in[1];
    const int*   batch = (const int*)d_in[2];
    // d_in[3] = num_hops (fixed 4)
    const float* atomT = (const float*)d_in[4];
    const float* wordT = (const float*)d_in[5];
    const float* W     = (const float*)d_in[6];
    const float* bias  = (const float*)d_in[7];

    const int N = in_sizes[0] / 2;
    const int E = in_sizes[1] / 2;
    const int G = out_size / D;

    const int* src = ei;
    const int* dst = ei + E;

    // workspace layout (16B-aligned starts)
    _Float16* fA16   = (_Float16*)d_ws;                  // N*D fp16
    _Float16* fB16   = fA16 + (size_t)N * D;             // N*D fp16
    float*    dinv   = (float*)(fB16 + (size_t)N * D);   // N
    float*    csr_w  = dinv + N;                         // E
    float*    W2     = csr_w + E;                        // D*D
    float*    W4     = W2 + D * D;                       // D*D
    float*    w1b    = W4 + D * D;                       // D
    float*    w2b    = w1b + D;                          // D
    float*    w3b    = w2b + D;                          // D
    float*    u1     = w3b + D;                          // N
    float*    u2     = u1 + N;                           // N
    float*    u3     = u2 + N;                           // N
    float*    pg4    = u3 + N;                           // G*D
    float*    pu     = pg4 + (size_t)G * D;              // 4*G
    int*      cnt    = (int*)(pu + 4 * G);               // N
    int*      off    = cnt + N;                          // N+1
    int*      cursor = off + N + 1;                      // N
    int*      csr_src= cursor + N;                       // E
    int*      start  = csr_src + E;                      // G+1

    const int B = 256;
    const int ndBlocks = (N * DC + B - 1) / B;
    const int nBlocks  = (N + B - 1) / B;

    embed_f16<<<ndBlocks, B, 0, stream>>>(x, (const float4*)atomT, (const float4*)wordT, (half4v*)fA16, N);

    hipMemsetAsync(cnt, 0, (size_t)N * sizeof(int), stream);
    cnt_kernel<<<(E + B - 1) / B, B, 0, stream>>>(dst, cnt, E);
    scan_kernel<<<1, 1024, 0, stream>>>(cnt, off, cursor, dinv, N);
    fill_kernel<<<(E + B - 1) / B, B, 0, stream>>>(src, dst, dinv, cursor, csr_src, csr_w, E);
    seg_start_kernel<<<nBlocks, B, 0, stream>>>(batch, start, N, G);

    wprep1<<<353, B, 0, stream>>>(W, bias, W2, w1b);
    wprep2<<<354, B, 0, stream>>>(W2, W, w1b, W4, w2b, w3b);

    // g_k = A_hat^k h0 (fp16 ping-pong), u_k fused into passes 1-3
    gather_f16<<<ndBlocks, B, 0, stream>>>((const half4v*)fA16, off, csr_src, csr_w, dinv,
                                           nullptr, u1, (half4v*)fB16, N);
    gather_f16<<<ndBlocks, B, 0, stream>>>((const half4v*)fB16, off, csr_src, csr_w, dinv,
                                           u1, u2, (half4v*)fA16, N);
    gather_f16<<<ndBlocks, B, 0, stream>>>((const half4v*)fA16, off, csr_src, csr_w, dinv,
                                           u2, u3, (half4v*)fB16, N);
    gather_f16<<<ndBlocks, B, 0, stream>>>((const half4v*)fB16, off, csr_src, csr_w, dinv,
                                           nullptr, nullptr, (half4v*)fA16, N);

    // pool first (linear), then tiny exact-fp32 GEMM on G rows
    pool_seg<<<G, B, 0, stream>>>((const half4v*)fA16, u1, u2, u3, start, pg4, pu, G);
    final_small<<<G, B, 0, stream>>>(pg4, pu, W4, w1b, w2b, w3b, bias, (float*)d_out, G);
}

// Round 14
// 384.250 us; speedup vs baseline: 1.6829x; 1.1379x over previous
//
#include <hip/hip_runtime.h>
#include <hip/hip_fp16.h>

#define D    300
#define DC   75    // D/4 half4 chunks per row
#define SCB  1024  // scan block size (elements per block)

typedef _Float16 half4v __attribute__((ext_vector_type(4)));

// ---------------- embedding -> fp16 h0 (compact N x D) ----------------
__global__ __launch_bounds__(256) void embed_f16(const int* __restrict__ x,
                                                 const float4* __restrict__ atomT,
                                                 const float4* __restrict__ wordT,
                                                 half4v* __restrict__ h, int N) {
    int idx = blockIdx.x * blockDim.x + threadIdx.x;
    if (idx >= N * DC) return;
    int n = idx / DC, c = idx - n * DC;
    int a = x[n * 2 + 0];
    int w = x[n * 2 + 1];
    float4 va = atomT[(size_t)a * DC + c];
    float4 vw = wordT[(size_t)w * DC + c];
    half4v o;
    o[0] = (_Float16)(va.x + vw.x);
    o[1] = (_Float16)(va.y + vw.y);
    o[2] = (_Float16)(va.z + vw.z);
    o[3] = (_Float16)(va.w + vw.w);
    h[idx] = o;
}

// ---------------- CSR build ----------------
__global__ __launch_bounds__(256) void cnt_kernel(const int* __restrict__ dst, int* __restrict__ cnt, int E) {
    int i = blockIdx.x * blockDim.x + threadIdx.x;
    if (i < E) atomicAdd(&cnt[dst[i]], 1);
}

// ---- parallel scan, phase 1: per-block exclusive scan + block sums + dinv ----
__global__ __launch_bounds__(SCB) void scan1_kernel(const int* __restrict__ cnt,
                                                    int* __restrict__ off, int* __restrict__ bsum,
                                                    float* __restrict__ dinv, int N) {
    __shared__ int warp_sums[16];
    const int tid = threadIdx.x;
    const int lane = tid & 63;
    const int wid = tid >> 6;
    int i = blockIdx.x * SCB + tid;
    int v = (i < N) ? cnt[i] : 0;
    if (i < N) dinv[i] = rsqrtf((float)(v + 1));   // +1 self-loop
    int s = v;
    #pragma unroll
    for (int d = 1; d < 64; d <<= 1) {
        int t = __shfl_up(s, d, 64);
        if (lane >= d) s += t;
    }
    if (lane == 63) warp_sums[wid] = s;
    __syncthreads();
    if (wid == 0) {
        int ws = (lane < 16) ? warp_sums[lane] : 0;
        #pragma unroll
        for (int d = 1; d < 16; d <<= 1) {
            int t = __shfl_up(ws, d, 64);
            if (lane >= d) ws += t;
        }
        if (lane < 16) warp_sums[lane] = ws;
    }
    __syncthreads();
    int excl = (wid ? warp_sums[wid - 1] : 0) + s - v;
    if (i < N) off[i] = excl;
    if (tid == SCB - 1) bsum[blockIdx.x] = warp_sums[15];
}
// ---- phase 2: single block scans block sums (nb <= 1024); off[N] = E exactly ----
__global__ __launch_bounds__(SCB) void scan2_kernel(int* __restrict__ bsum, int* __restrict__ bbase,
                                                    int* __restrict__ off, int nb, int N, int E) {
    __shared__ int warp_sums[16];
    const int tid = threadIdx.x;
    const int lane = tid & 63;
    const int wid = tid >> 6;
    int v = (tid < nb) ? bsum[tid] : 0;
    int s = v;
    #pragma unroll
    for (int d = 1; d < 64; d <<= 1) {
        int t = __shfl_up(s, d, 64);
        if (lane >= d) s += t;
    }
    if (lane == 63) warp_sums[wid] = s;
    __syncthreads();
    if (wid == 0) {
        int ws = (lane < 16) ? warp_sums[lane] : 0;
        #pragma unroll
        for (int d = 1; d < 16; d <<= 1) {
            int t = __shfl_up(ws, d, 64);
            if (lane >= d) ws += t;
        }
        if (lane < 16) warp_sums[lane] = ws;
    }
    __syncthreads();
    if (tid < nb) bbase[tid] = (wid ? warp_sums[wid - 1] : 0) + s - v;
    if (tid == 0) off[N] = E;   // sum of cnt == E identically
}
// ---- phase 3: add block bases; init cursor ----
__global__ __launch_bounds__(256) void scan3_kernel(int* __restrict__ off, const int* __restrict__ bbase,
                                                    int* __restrict__ cursor, int N) {
    int i = blockIdx.x * blockDim.x + threadIdx.x;
    if (i >= N) return;
    int o = off[i] + bbase[i >> 10];
    off[i] = o;
    cursor[i] = o;
}

__global__ __launch_bounds__(256) void fill_kernel(const int* __restrict__ src, const int* __restrict__ dst,
                                                   const float* __restrict__ dinv, int* __restrict__ cursor,
                                                   int* __restrict__ csr_src, float* __restrict__ csr_w, int E) {
    int e = blockIdx.x * blockDim.x + threadIdx.x;
    if (e >= E) return;
    int s = src[e], d = dst[e];
    int slot = atomicAdd(&cursor[d], 1);
    csr_src[slot] = s;
    csr_w[slot] = dinv[s] * dinv[d];
}
__global__ __launch_bounds__(256) void seg_start_kernel(const int* __restrict__ batch,
                                                        int* __restrict__ start, int N, int G) {
    int i = blockIdx.x * blockDim.x + threadIdx.x;
    if (i >= N) return;
    int b = batch[i];
    int prev = (i == 0) ? -1 : batch[i - 1];
    for (int g = prev + 1; g <= b; ++g) start[g] = i;
    if (i == N - 1)
        for (int g = b + 1; g <= G; ++g) start[g] = N;
}

// ---------------- W-prep (2 kernels, all fp32) ----------------
// K1: W2 = W@W ; w1b = b@W
__global__ __launch_bounds__(256) void wprep1(const float* __restrict__ W, const float* __restrict__ bias,
                                              float* __restrict__ W2, float* __restrict__ w1b) {
    int bid = blockIdx.x;
    if (bid < 352) {
        int id = bid * 256 + threadIdx.x;
        if (id >= D * D) return;
        int i = id / D, j = id % D;
        float acc = 0.f;
        #pragma unroll 4
        for (int k = 0; k < D; ++k) acc = fmaf(W[i * D + k], W[k * D + j], acc);
        W2[id] = acc;
    } else {
        int j = threadIdx.x;
        if (j >= D) return;
        float acc = 0.f;
        #pragma unroll 4
        for (int k = 0; k < D; ++k) acc = fmaf(bias[k], W[k * D + j], acc);
        w1b[j] = acc;
    }
}
// K2: W4 = W2@W2 ; w2b = w1b@W ; w3b = w1b@W2
__global__ __launch_bounds__(256) void wprep2(const float* __restrict__ W2, const float* __restrict__ W,
                                              const float* __restrict__ w1b,
                                              float* __restrict__ W4, float* __restrict__ w2b,
                                              float* __restrict__ w3b) {
    int bid = blockIdx.x;
    if (bid < 352) {
        int id = bid * 256 + threadIdx.x;
        if (id >= D * D) return;
        int i = id / D, j = id % D;
        float acc = 0.f;
        #pragma unroll 4
        for (int k = 0; k < D; ++k) acc = fmaf(W2[i * D + k], W2[k * D + j], acc);
        W4[id] = acc;
    } else if (bid == 352) {
        int j = threadIdx.x;
        if (j >= D) return;
        float acc = 0.f;
        #pragma unroll 4
        for (int k = 0; k < D; ++k) acc = fmaf(w1b[k], W[k * D + j], acc);
        w2b[j] = acc;
    } else {
        int j = threadIdx.x;
        if (j >= D) return;
        float acc = 0.f;
        #pragma unroll 4
        for (int k = 0; k < D; ++k) acc = fmaf(w1b[k], W2[k * D + j], acc);
        w3b[j] = acc;
    }
}

// ---------------- sparse hop (fp16 rows, compact), optional fused scalar-u ----------------
__global__ __launch_bounds__(256) void gather_f16(const half4v* __restrict__ in,
                                                  const int* __restrict__ off,
                                                  const int* __restrict__ csr_src,
                                                  const float* __restrict__ csr_w,
                                                  const float* __restrict__ dinv,
                                                  const float* __restrict__ uin,
                                                  float* __restrict__ uout,
                                                  half4v* __restrict__ out, int N) {
    int idx = blockIdx.x * blockDim.x + threadIdx.x;
    if (idx >= N * DC) return;
    int n = idx / DC, c = idx - n * DC;
    float s = dinv[n]; s = s * s;
    half4v v0 = in[idx];
    float4 acc = make_float4(s * (float)v0[0], s * (float)v0[1], s * (float)v0[2], s * (float)v0[3]);
    const bool dou = (uout != nullptr) && (c == 0);
    float uacc = 0.f;
    if (dou) uacc = s * (uin ? uin[n] : 1.0f);
    int j0 = off[n], j1 = off[n + 1];
    for (int j = j0; j < j1; ++j) {
        int sn = csr_src[j];
        float w = csr_w[j];
        half4v u = in[(size_t)sn * DC + c];
        acc.x += w * (float)u[0]; acc.y += w * (float)u[1];
        acc.z += w * (float)u[2]; acc.w += w * (float)u[3];
        if (dou) uacc += w * (uin ? uin[sn] : 1.0f);
    }
    half4v o;
    o[0] = (_Float16)acc.x; o[1] = (_Float16)acc.y;
    o[2] = (_Float16)acc.z; o[3] = (_Float16)acc.w;
    out[idx] = o;
    if (dou) uout[n] = uacc;
}

// ---------------- pool g4 + u's per graph (segment means) ----------------
__global__ __launch_bounds__(256) void pool_seg(const half4v* __restrict__ g4,
                                                const float* __restrict__ u1,
                                                const float* __restrict__ u2,
                                                const float* __restrict__ u3,
                                                const int* __restrict__ start,
                                                float* __restrict__ pg4, float* __restrict__ pu, int G) {
    int g = blockIdx.x;
    if (g >= G) return;
    int j0 = start[g], j1 = start[g + 1];
    float inv = (j1 > j0) ? 1.0f / (float)(j1 - j0) : 0.0f;
    int tid = threadIdx.x;
    if (tid < DC) {
        float4 acc = make_float4(0.f, 0.f, 0.f, 0.f);
        for (int n = j0; n < j1; ++n) {
            half4v v = g4[(size_t)n * DC + tid];
            acc.x += (float)v[0]; acc.y += (float)v[1];
            acc.z += (float)v[2]; acc.w += (float)v[3];
        }
        float4 o = make_float4(acc.x * inv, acc.y * inv, acc.z * inv, acc.w * inv);
        *(float4*)&pg4[(size_t)g * D + tid * 4] = o;
    } else if (tid == DC || tid == DC + 1 || tid == DC + 2) {
        const float* u = (tid == DC) ? u1 : (tid == DC + 1) ? u2 : u3;
        float acc = 0.f;
        for (int n = j0; n < j1; ++n) acc += u[n];
        pu[g * 4 + (tid - DC)] = acc * inv;
    } else if (tid == DC + 3) {
        pu[g * 4 + 3] = (j1 > j0) ? 1.0f : 0.0f;
    }
}

// ---------------- final small GEMM (fp32, exact): out = pg4@W4 + rank-1 terms ----------------
__global__ __launch_bounds__(256) void final_small(const float* __restrict__ pg4,
                                                   const float* __restrict__ pu,
                                                   const float* __restrict__ W4,
                                                   const float* __restrict__ w1b,
                                                   const float* __restrict__ w2b,
                                                   const float* __restrict__ w3b,
                                                   const float* __restrict__ bias,
                                                   float* __restrict__ out, int G) {
    __shared__ float row[D];
    int g = blockIdx.x;
    if (g >= G) return;
    int tid = threadIdx.x;
    for (int c = tid; c < D; c += 256) row[c] = pg4[(size_t)g * D + c];
    __syncthreads();
    float p1 = pu[g * 4 + 0], p2 = pu[g * 4 + 1], p3 = pu[g * 4 + 2], fl = pu[g * 4 + 3];
    for (int j = tid; j < D; j += 256) {
        float acc = 0.f;
        #pragma unroll 4
        for (int k = 0; k < D; ++k) acc = fmaf(row[k], W4[(size_t)k * D + j], acc);
        out[(size_t)g * D + j] = acc + p1 * w1b[j] + p2 * w2b[j] + p3 * w3b[j] + fl * bias[j];
    }
}

extern "C" void kernel_launch(void* const* d_in, const int* in_sizes, int n_in,
                              void* d_out, int out_size, void* d_ws, size_t ws_size,
                              hipStream_t stream) {
    (void)n_in; (void)ws_size;
    const int*   x     = (const int*)d_in[0];
    const int*   ei    = (const int*)d_in[1];
    const int*   batch = (const int*)d_in[2];
    // d_in[3] = num_hops (fixed 4)
    const float* atomT = (const float*)d_in[4];
    const float* wordT = (const float*)d_in[5];
    const float* W     = (const float*)d_in[6];
    const float* bias  = (const float*)d_in[7];

    const int N = in_sizes[0] / 2;
    const int E = in_sizes[1] / 2;
    const int G = out_size / D;

    const int* src = ei;
    const int* dst = ei + E;

    // workspace layout (16B-aligned starts)
    _Float16* fA16   = (_Float16*)d_ws;                  // N*D fp16
    _Float16* fB16   = fA16 + (size_t)N * D;             // N*D fp16
    float*    dinv   = (float*)(fB16 + (size_t)N * D);   // N
    float*    csr_w  = dinv + N;                         // E
    float*    W2     = csr_w + E;                        // D*D
    float*    W4     = W2 + D * D;                       // D*D
    float*    w1b    = W4 + D * D;                       // D
    float*    w2b    = w1b + D;                          // D
    float*    w3b    = w2b + D;                          // D
    float*    u1     = w3b + D;                          // N
    float*    u2     = u1 + N;                           // N
    float*    u3     = u2 + N;                           // N
    float*    pg4    = u3 + N;                           // G*D
    float*    pu     = pg4 + (size_t)G * D;              // 4*G
    int*      cnt    = (int*)(pu + 4 * G);               // N
    int*      off    = cnt + N;                          // N+1
    int*      cursor = off + N + 1;                      // N
    int*      csr_src= cursor + N;                       // E
    int*      bsum   = csr_src + E;                      // <=1024
    int*      bbase  = bsum + 1024;                      // <=1024
    int*      start  = bbase + 1024;                     // G+1

    const int B = 256;
    const int ndBlocks = (N * DC + B - 1) / B;
    const int nBlocks  = (N + B - 1) / B;
    const int nbScan   = (N + SCB - 1) / SCB;

    embed_f16<<<ndBlocks, B, 0, stream>>>(x, (const float4*)atomT, (const float4*)wordT, (half4v*)fA16, N);

    hipMemsetAsync(cnt, 0, (size_t)N * sizeof(int), stream);
    cnt_kernel<<<(E + B - 1) / B, B, 0, stream>>>(dst, cnt, E);
    scan1_kernel<<<nbScan, SCB, 0, stream>>>(cnt, off, bsum, dinv, N);
    scan2_kernel<<<1, SCB, 0, stream>>>(bsum, bbase, off, nbScan, N, E);
    scan3_kernel<<<nBlocks, B, 0, stream>>>(off, bbase, cursor, N);
    fill_kernel<<<(E + B - 1) / B, B, 0, stream>>>(src, dst, dinv, cursor, csr_src, csr_w, E);
    seg_start_kernel<<<nBlocks, B, 0, stream>>>(batch, start, N, G);

    wprep1<<<353, B, 0, stream>>>(W, bias, W2, w1b);
    wprep2<<<354, B, 0, stream>>>(W2, W, w1b, W4, w2b, w3b);

    // g_k = A_hat^k h0 (fp16 ping-pong), u_k fused into passes 1-3
    gather_f16<<<ndBlocks, B, 0, stream>>>((const half4v*)fA16, off, csr_src, csr_w, dinv,
                                           nullptr, u1, (half4v*)fB16, N);
    gather_f16<<<ndBlocks, B, 0, stream>>>((const half4v*)fB16, off, csr_src, csr_w, dinv,
                                           u1, u2, (half4v*)fA16, N);
    gather_f16<<<ndBlocks, B, 0, stream>>>((const half4v*)fA16, off, csr_src, csr_w, dinv,
                                           u2, u3, (half4v*)fB16, N);
    gather_f16<<<ndBlocks, B, 0, stream>>>((const half4v*)fB16, off, csr_src, csr_w, dinv,
                                           nullptr, nullptr, (half4v*)fA16, N);

    // pool first (linear), then tiny exact-fp32 GEMM on G rows
    pool_seg<<<G, B, 0, stream>>>((const half4v*)fA16, u1, u2, u3, start, pg4, pu, G);
    final_small<<<G, B, 0, stream>>>(pg4, pu, W4, w1b, w2b, w3b, bias, (float*)d_out, G);
}